// Round 5
// baseline (525.346 us; speedup 1.0000x reference)
//
#include <hip/hip_runtime.h>

#define NB 32
#define PP 8192
#define OPP 2048

typedef _Float16 f16;
typedef f16 half8 __attribute__((ext_vector_type(8)));
typedef f16 half4 __attribute__((ext_vector_type(4)));
typedef f16 half2v __attribute__((ext_vector_type(2)));
typedef float f32x4 __attribute__((ext_vector_type(4)));

#define MFMA16(a, b, c) __builtin_amdgcn_mfma_f32_16x16x32_f16(a, b, c, 0, 0, 0)

// ======= conv weight prep: [co][ci][3][3] fp32 -> MFMA B-fragment order fp16 =======
template <int CO, int CI>
__global__ __launch_bounds__(256) void wfragprep_k(const float* __restrict__ wsrc,
                                                   f16* __restrict__ wf) {
  __shared__ float tile[CI * 9];
  int co = blockIdx.x, t = threadIdx.x;
  const float* src = wsrc + (size_t)co * CI * 9;
  for (int i = t; i < CI * 9; i += 256) tile[i] = src[i];
  __syncthreads();
  constexpr int NBB = CO / 16;
  int nb = co >> 4, l16 = co & 15;
  for (int e = t; e < (CI / 32) * 9 * 4; e += 256) {
    int quad = e & 3;
    int kk = (e >> 2) % 9;
    int cic = e / 36;
    half8 v;
#pragma unroll
    for (int j = 0; j < 8; ++j) {
      int ci = cic * 32 + quad * 8 + j;
      v[j] = (f16)tile[ci * 9 + kk];
    }
    *(half8*)(wf + ((((size_t)cic * 9 + kk) * NBB + nb) * 64 + quad * 16 + l16) * 8) = v;
  }
}

__global__ void cvt16_k(const float* __restrict__ in, f16* __restrict__ out, int n4) {
  int idx = blockIdx.x * 256 + threadIdx.x;
  if (idx >= n4) return;
  float4 v = ((const float4*)in)[idx];
  half4 h; h.x = (f16)v.x; h.y = (f16)v.y; h.z = (f16)v.z; h.w = (f16)v.w;
  ((half4*)out)[idx] = h;
}

// cls_w1 scene part [1024][1538] -> [1024][1024] fp16
__global__ void cw1prep_k(const float* __restrict__ w, f16* __restrict__ out) {
  int idx = blockIdx.x * 256 + threadIdx.x;
  if (idx >= 1024 * 1024) return;
  int co = idx >> 10, k = idx & 1023;
  out[idx] = (f16)w[(size_t)co * 1538 + k];
}

// convt_w [o][i][a'][b'] -> MFMA B-fragment layout
__global__ void ctprep_k(const float* __restrict__ w, f16* __restrict__ out) {
  int idx = blockIdx.x * 256 + threadIdx.x;
  if (idx >= 2048 * 1024) return;
  int j = idx & 7, l = (idx >> 3) & 63, kb = (idx >> 9) & 31, nb = idx >> 14;
  int n16 = l & 15, quad = l >> 4;
  int np = nb * 16 + n16;
  int k = kb * 32 + quad * 8 + j;
  int p = np >> 9, o = np & 511;
  out[idx] = (f16)w[((size_t)o * 1024 + k) * 4 + (3 - p)];
}

// ======================= object-cloud mean =======================
__global__ void ocmean_k(const float* __restrict__ oc, float* __restrict__ ocm) {
  int n = blockIdx.x, t = threadIdx.x;
  __shared__ float sx[256], sy[256];
  float ax = 0.f, ay = 0.f;
  for (int p = t; p < OPP; p += 256) {
    ax += oc[((size_t)n * OPP + p) * 2 + 0];
    ay += oc[((size_t)n * OPP + p) * 2 + 1];
  }
  sx[t] = ax; sy[t] = ay;
  __syncthreads();
  for (int s = 128; s > 0; s >>= 1) {
    if (t < s) { sx[t] += sx[t + s]; sy[t] += sy[t + s]; }
    __syncthreads();
  }
  if (t == 0) {
    ocm[n * 2 + 0] = sx[0] / (float)OPP;
    ocm[n * 2 + 1] = sy[0] / (float)OPP;
  }
}

// ======================= voxel PointNet: barrier-free LDS scatter-max =======================
__global__ __launch_bounds__(256) void pointnet_lds_k(
    const float* __restrict__ sc, const float* __restrict__ w1, const float* __restrict__ b1,
    const f16* __restrict__ w2h, const float* __restrict__ b2, float* __restrict__ voxg) {
  __shared__ float voxl[400 * 33];         // 52,800 B
  int t = threadIdx.x, lane = t & 63, w = t >> 6;
  int quad = lane >> 4, l16 = lane & 15;
  int b = blockIdx.x;
  int ps = b & 3, cg = (b >> 2) & 7, n = b >> 5;
  // packed layer-1 weights: this quad's 32 channels => 16 half2 per array
  half2v w1x2[16], w1y2[16], b12[16];
#pragma unroll
  for (int i = 0; i < 16; ++i) {
    int k0 = (i >> 2) * 32 + quad * 8 + (i & 3) * 2;   // ks = i>>2, j2 = i&3
    w1x2[i] = (half2v){(f16)w1[k0 * 2], (f16)w1[(k0 + 1) * 2]};
    w1y2[i] = (half2v){(f16)w1[k0 * 2 + 1], (f16)w1[(k0 + 1) * 2 + 1]};
    b12[i]  = (half2v){(f16)b1[k0], (f16)b1[k0 + 1]};
  }
  half8 bf[2][4];
  float bias[2];
#pragma unroll
  for (int nt = 0; nt < 2; ++nt) {
    int ch = cg * 32 + nt * 16 + l16;
    bias[nt] = b2[ch];
#pragma unroll
    for (int ks = 0; ks < 4; ++ks)
      bf[nt][ks] = *(const half8*)(w2h + (size_t)ch * 128 + ks * 32 + quad * 8);
  }
  for (int i = t; i < 400 * 33; i += 256) voxl[i] = 0.0f;
  __syncthreads();
  const half2v z2 = {};
  const float* scp = sc + ((size_t)n * PP + (size_t)ps * 2048) * 2;
  int p0 = w * 16 + l16;
  float2 xy = *(const float2*)(scp + p0 * 2);
  for (int it = 0; it < 32; ++it) {
    float x = xy.x, y = xy.y;
    if (it < 31) xy = *(const float2*)(scp + ((it + 1) * 64 + p0) * 2);
    float bif = fminf(fmaxf(ceilf((x + 0.5f) * 20.0f) - 1.0f, 0.0f), 19.0f);
    float bjf = fminf(fmaxf(ceilf((y + 0.5f) * 20.0f) - 1.0f, 0.0f), 19.0f);
    bool valid = (x > -0.5f) && (x <= 0.5f) && (y > -0.5f) && (y <= 0.5f);
    float px = x - (-0.5f + (bif + 0.5f) * 0.05f);
    float py = y - (-0.5f + (bjf + 0.5f) * 0.05f);
    int bn = valid ? ((int)bif * 20 + (int)bjf) : -1;
    f16 pxh = (f16)px, pyh = (f16)py;
    half2v px2 = (half2v){pxh, pxh}, py2 = (half2v){pyh, pyh};
    f32x4 acc0 = {}, acc1 = {};
#pragma unroll
    for (int ks = 0; ks < 4; ++ks) {
      half8 af;
#pragma unroll
      for (int j2 = 0; j2 < 4; ++j2) {
        half2v tmp = w1x2[ks * 4 + j2] * px2 + (w1y2[ks * 4 + j2] * py2 + b12[ks * 4 + j2]);
        tmp = __builtin_elementwise_max(tmp, z2);
        reinterpret_cast<half2v*>(&af)[j2] = tmp;
      }
      acc0 = MFMA16(af, bf[0][ks], acc0);
      acc1 = MFMA16(af, bf[1][ks], acc1);
    }
#pragma unroll
    for (int r = 0; r < 4; ++r) {
      int bn2 = __shfl(bn, quad * 4 + r);
      if (bn2 >= 0) {
        float v0 = fmaxf(acc0[r] + bias[0], 0.0f);
        float v1 = fmaxf(acc1[r] + bias[1], 0.0f);
        atomicMax((int*)voxl + bn2 * 33 + l16, __float_as_int(v0));
        atomicMax((int*)voxl + bn2 * 33 + 16 + l16, __float_as_int(v1));
      }
    }
  }
  __syncthreads();
  // merge private LDS grid into the global fp32 voxel buffer
  float* vg = voxg + ((size_t)n * 400) * 256 + cg * 32;
  for (int i = t; i < 400 * 32; i += 256) {
    int bin = i >> 5, c = i & 31;
    float v = voxl[bin * 33 + c];
    if (v > 0.0f)
      atomicMax((int*)(vg + (size_t)bin * 256) + c, __float_as_int(v));
  }
}

// ======================= MFMA implicit-GEMM conv 3x3 pad1 + relu =======================
template <int H, int W, int CI, int CO, int MSPLIT>
__global__ __launch_bounds__(256, 2) void convmfma_k(
    const f16* __restrict__ inh, const f16* __restrict__ wf,
    const float* __restrict__ bias, f16* __restrict__ outh) {
  constexpr int HS = H / MSPLIT;
  constexpr int Mpix = HS * W;
  constexpr int MT = (Mpix + 15) / 16;
  constexpr int PR = HS + 2, PC = W + 2;
  constexpr int NCIC = CI / 32;
  constexpr int COG = CO / 128;
  constexpr int NBB = CO / 16;
  extern __shared__ char smem[];
  f16* Ap = (f16*)smem;                          // [PR*PC][40]
  int b = blockIdx.x;
  int cog = b % COG;
  int ms = (b / COG) % MSPLIT;
  int n = b / (COG * MSPLIT);
  int co0 = cog * 128;
  int r0 = ms * HS;
  int t = threadIdx.x, lane = t & 63, w = t >> 6;
  int quad = lane >> 4, l16 = lane & 15;
  int nb0 = cog * 8 + w * 2;                     // B-fragment row-block (16 co each)

  int abase[MT];
#pragma unroll
  for (int mi = 0; mi < MT; ++mi) {
    int pl = mi * 16 + l16; if (pl > Mpix - 1) pl = Mpix - 1;
    int y = pl / W, x = pl - y * W;
    abase[mi] = (y * PC + x) * 40 + quad * 8;    // halves
  }
  f32x4 acc[MT][2] = {};

  const f16* inbase = inh + (size_t)n * H * W * CI;

  for (int cic = 0; cic < NCIC; ++cic) {
    __syncthreads();                             // protect Ap from prior reads
    for (int cell = t; cell < PR * PC; cell += 256) {
      int pr = cell / PC, pc = cell - pr * PC;
      int yin = r0 - 1 + pr, xin = pc - 1;
      uint4 d0 = {0,0,0,0}, d1 = {0,0,0,0}, d2 = {0,0,0,0}, d3 = {0,0,0,0};
      if (yin >= 0 && yin < H && xin >= 0 && xin < W) {
        const uint4* src = (const uint4*)(inbase + ((size_t)yin * W + xin) * CI + cic * 32);
        d0 = src[0]; d1 = src[1]; d2 = src[2]; d3 = src[3];
      }
      uint4* dst = (uint4*)(Ap + cell * 40);
      dst[0] = d0; dst[1] = d1; dst[2] = d2; dst[3] = d3;
    }
    __syncthreads();
    const f16* wfc = wf + (size_t)(cic * 9) * NBB * 512;
#pragma unroll
    for (int ky = 0; ky < 3; ++ky)
#pragma unroll
      for (int kx = 0; kx < 3; ++kx) {
        int kk = ky * 3 + kx;
        half8 bf0 = *(const half8*)(wfc + ((size_t)(kk * NBB + nb0) * 64 + lane) * 8);
        half8 bf1 = *(const half8*)(wfc + ((size_t)(kk * NBB + nb0 + 1) * 64 + lane) * 8);
        int shift = (ky * PC + kx) * 40;
#pragma unroll
        for (int mi = 0; mi < MT; ++mi) {
          half8 af = *(const half8*)(Ap + abase[mi] + shift);
          acc[mi][0] = MFMA16(af, bf0, acc[mi][0]);
          acc[mi][1] = MFMA16(af, bf1, acc[mi][1]);
        }
      }
  }
  int co_w = co0 + w * 32;
  float bv0 = bias[co_w + l16];
  float bv1 = bias[co_w + 16 + l16];
  f16* ob = outh + ((size_t)n * H * W + (size_t)ms * Mpix) * CO;
#pragma unroll
  for (int mi = 0; mi < MT; ++mi) {
#pragma unroll
    for (int r = 0; r < 4; ++r) {
      int p = mi * 16 + quad * 4 + r;
      if (p < Mpix) {
        float v0 = acc[mi][0][r] + bv0; v0 = v0 > 0.f ? v0 : 0.f;
        float v1 = acc[mi][1][r] + bv1; v1 = v1 > 0.f ? v1 : 0.f;
        ob[(size_t)p * CO + co_w + l16] = (f16)v0;
        ob[(size_t)p * CO + co_w + 16 + l16] = (f16)v1;
      }
    }
  }
}

// ======================= maxpool 2x2 (+ fused pack into scene buffer) =======================
__global__ void pool1_k(const f16* __restrict__ g1, f16* __restrict__ f1h,
                        f16* __restrict__ scnh) {
  int idx = blockIdx.x * 256 + threadIdx.x;
  if (idx >= 32 * 100 * 256) return;
  int c2 = idx & 255, rem = idx >> 8;
  int op = rem % 100, n = rem / 100;
  int py = op / 10, px = op - py * 10;
  const f16* base = g1 + (((size_t)n * 400 + (size_t)(2 * py) * 20 + 2 * px) * 512) + c2 * 2;
  float a0 = (float)base[0],   a1 = (float)base[1];
  float b0 = (float)base[512], b1 = (float)base[513];
  const f16* base2 = base + 20 * 512;
  float c0 = (float)base2[0],   c1 = (float)base2[1];
  float d0 = (float)base2[512], d1 = (float)base2[513];
  union { f16 h[2]; unsigned u; } pk;
  pk.h[0] = (f16)fmaxf(fmaxf(a0, b0), fmaxf(c0, d0));
  pk.h[1] = (f16)fmaxf(fmaxf(a1, b1), fmaxf(c1, d1));
  *(unsigned*)(f1h + ((size_t)n * 100 + op) * 512 + c2 * 2) = pk.u;
  *(unsigned*)(scnh + ((size_t)n * 100 + op) * 1024 + c2 * 2) = pk.u;
}

__global__ void pool2_k(const f16* __restrict__ g2, f16* __restrict__ f2h) {
  int idx = blockIdx.x * 256 + threadIdx.x;
  if (idx >= 32 * 25 * 512) return;
  int c2 = idx & 511, rem = idx >> 9;
  int op = rem % 25, n = rem / 25;
  int py = op / 5, px = op - py * 5;
  const f16* base = g2 + (((size_t)n * 100 + (size_t)(2 * py) * 10 + 2 * px) * 1024) + c2 * 2;
  float a0 = (float)base[0],    a1 = (float)base[1];
  float b0 = (float)base[1024], b1 = (float)base[1025];
  const f16* base2 = base + 10 * 1024;
  float c0 = (float)base2[0],    c1 = (float)base2[1];
  float d0 = (float)base2[1024], d1 = (float)base2[1025];
  f16* o = f2h + ((size_t)n * 25 + op) * 1024 + c2 * 2;
  o[0] = (f16)fmaxf(fmaxf(a0, b0), fmaxf(c0, d0));
  o[1] = (f16)fmaxf(fmaxf(a1, b1), fmaxf(c1, d1));
}

// ======================= conv transpose 2x2 s2 (1024->512), MFMA v2 =======================
__global__ __launch_bounds__(256, 2) void convt_mfma_k(
    const f16* __restrict__ f2h, const f16* __restrict__ ctwf,
    const float* __restrict__ ctb, f16* __restrict__ scnh) {
  __shared__ f16 act[25 * 1048];           // 52,400 B
  int b = blockIdx.x;
  int ng = b & 15, n = b >> 4;
  int t = threadIdx.x, lane = t & 63, w = t >> 6;
  int quad = lane >> 4, l16 = lane & 15;
  for (int i = t; i < 25 * 128; i += 256) {
    int row = i >> 7, c8 = i & 127;
    *(half8*)(act + row * 1048 + c8 * 8) =
        *(const half8*)(f2h + ((size_t)n * 25 + row) * 1024 + c8 * 8);
  }
  __syncthreads();
  int r1 = 16 + (l16 > 8 ? 8 : l16);       // clamp: garbage rows never stored
  f32x4 acc[2][2] = {};
  const f16* wp0 = ctwf + ((size_t)((ng * 8 + w * 2 + 0) * 32) * 64 + lane) * 8;
  const f16* wp1 = ctwf + ((size_t)((ng * 8 + w * 2 + 1) * 32) * 64 + lane) * 8;
#pragma unroll 4
  for (int ks = 0; ks < 32; ++ks) {
    half8 a0 = *(const half8*)(act + l16 * 1048 + ks * 32 + quad * 8);
    half8 a1 = *(const half8*)(act + r1 * 1048 + ks * 32 + quad * 8);
    half8 b0 = *(const half8*)(wp0 + (size_t)ks * 512);
    half8 b1 = *(const half8*)(wp1 + (size_t)ks * 512);
    acc[0][0] = MFMA16(a0, b0, acc[0][0]);
    acc[1][0] = MFMA16(a1, b0, acc[1][0]);
    acc[0][1] = MFMA16(a0, b1, acc[0][1]);
    acc[1][1] = MFMA16(a1, b1, acc[1][1]);
  }
#pragma unroll
  for (int nt = 0; nt < 2; ++nt) {
    int np = ng * 128 + w * 32 + nt * 16 + l16;
    int p = np >> 9, co = np & 511;
    int a = p >> 1, bc = p & 1;
    float bb = ctb[co];
#pragma unroll
    for (int mt = 0; mt < 2; ++mt)
#pragma unroll
      for (int r = 0; r < 4; ++r) {
        int px = mt * 16 + quad * 4 + r;
        if (px < 25) {
          int ph = px / 5, pw = px - ph * 5;
          int opx = (2 * ph + a) * 10 + 2 * pw + bc;
          scnh[((size_t)n * 100 + opx) * 1024 + 512 + co] = (f16)(acc[mt][nt][r] + bb);
        }
      }
  }
}

// ======================= object SA: fused 4-layer MFMA + max (M=64 tiles) =======================
__global__ __launch_bounds__(256, 2) void sa_mfma_k(
    const float* __restrict__ oc, const float* __restrict__ ocm,
    const float* __restrict__ w1, const float* __restrict__ b1,
    const f16* __restrict__ w2h, const float* __restrict__ b2,
    const f16* __restrict__ w3h, const float* __restrict__ b3,
    const f16* __restrict__ w4h, const float* __restrict__ b4,
    float* __restrict__ obj) {
  __shared__ f16 act1[64 * 72];            // 9,216 B [pt][K=64]
  __shared__ f16 act2[64 * 136];           // 17,408 B [pt][K=128]
  __shared__ f16 act3[64 * 264];           // 33,792 B [pt][K=256]
  __shared__ float pcx[64], pcy[64];
  int b = blockIdx.x;                      // 1024 = 32 n * 32 chunks of 64 pts
  int n = b >> 5, pb = (b & 31) * 64;
  int t = threadIdx.x, lane = t & 63, w = t >> 6;
  int quad = lane >> 4, l16 = lane & 15;
  if (t < 64) {
    pcx[t] = oc[((size_t)n * OPP + pb + t) * 2 + 0] - ocm[n * 2 + 0];
    pcy[t] = oc[((size_t)n * OPP + pb + t) * 2 + 1] - ocm[n * 2 + 1];
  }
  __syncthreads();
  {                                        // layer1: 2 -> 64 for 64 points
    int c = t & 63, pg = t >> 6;
    float wx = w1[c * 2], wy = w1[c * 2 + 1], bb = b1[c];
#pragma unroll
    for (int j = 0; j < 16; ++j) {
      int p = pg * 16 + j;
      act1[p * 72 + c] = (f16)fmaxf(fmaf(wx, pcx[p], fmaf(wy, pcy[p], bb)), 0.0f);
    }
  }
  __syncthreads();
  {                                        // layer2: M=64, K=64, N=128; wave n-range 32
    int n0 = w * 32;
    f32x4 acc[4][2] = {};
#pragma unroll
    for (int ks = 0; ks < 2; ++ks) {
      half8 a[4];
#pragma unroll
      for (int mt = 0; mt < 4; ++mt)
        a[mt] = *(const half8*)(act1 + (mt * 16 + l16) * 72 + ks * 32 + quad * 8);
#pragma unroll
      for (int nt = 0; nt < 2; ++nt) {
        half8 bf = *(const half8*)(w2h + (size_t)(n0 + nt * 16 + l16) * 64 + ks * 32 + quad * 8);
#pragma unroll
        for (int mt = 0; mt < 4; ++mt)
          acc[mt][nt] = MFMA16(a[mt], bf, acc[mt][nt]);
      }
    }
#pragma unroll
    for (int nt = 0; nt < 2; ++nt) {
      int col = n0 + nt * 16 + l16;
      float bb = b2[col];
#pragma unroll
      for (int mt = 0; mt < 4; ++mt)
#pragma unroll
        for (int r = 0; r < 4; ++r)
          act2[(mt * 16 + quad * 4 + r) * 136 + col] = (f16)fmaxf(acc[mt][nt][r] + bb, 0.0f);
    }
  }
  __syncthreads();
  {                                        // layer3: M=64, K=128, N=256; wave n-range 64
    int n0 = w * 64;
    f32x4 acc[4][4] = {};
#pragma unroll
    for (int ks = 0; ks < 4; ++ks) {
      half8 a[4];
#pragma unroll
      for (int mt = 0; mt < 4; ++mt)
        a[mt] = *(const half8*)(act2 + (mt * 16 + l16) * 136 + ks * 32 + quad * 8);
#pragma unroll
      for (int nt = 0; nt < 4; ++nt) {
        half8 bf = *(const half8*)(w3h + (size_t)(n0 + nt * 16 + l16) * 128 + ks * 32 + quad * 8);
#pragma unroll
        for (int mt = 0; mt < 4; ++mt)
          acc[mt][nt] = MFMA16(a[mt], bf, acc[mt][nt]);
      }
    }
#pragma unroll
    for (int nt = 0; nt < 4; ++nt) {
      int col = n0 + nt * 16 + l16;
      float bb = b3[col];
#pragma unroll
      for (int mt = 0; mt < 4; ++mt)
#pragma unroll
        for (int r = 0; r < 4; ++r)
          act3[(mt * 16 + quad * 4 + r) * 264 + col] = (f16)fmaxf(acc[mt][nt][r] + bb, 0.0f);
    }
  }
  __syncthreads();
  {                                        // layer4: M=64, K=256, N=512; wave n-range 128; + max
    int n0 = w * 128;
    f32x4 acc[4][8] = {};
#pragma unroll
    for (int ks = 0; ks < 8; ++ks) {
      half8 a[4];
#pragma unroll
      for (int mt = 0; mt < 4; ++mt)
        a[mt] = *(const half8*)(act3 + (mt * 16 + l16) * 264 + ks * 32 + quad * 8);
#pragma unroll
      for (int nt = 0; nt < 8; ++nt) {
        half8 bf = *(const half8*)(w4h + (size_t)(n0 + nt * 16 + l16) * 256 + ks * 32 + quad * 8);
#pragma unroll
        for (int mt = 0; mt < 4; ++mt)
          acc[mt][nt] = MFMA16(a[mt], bf, acc[mt][nt]);
      }
    }
#pragma unroll
    for (int nt = 0; nt < 8; ++nt) {
      int col = n0 + nt * 16 + l16;
      float bb = b4[col];
      float v = 0.0f;
#pragma unroll
      for (int mt = 0; mt < 4; ++mt)
#pragma unroll
        for (int r = 0; r < 4; ++r)
          v = fmaxf(v, acc[mt][nt][r] + bb);
      v = fmaxf(v, 0.0f);
      v = fmaxf(v, __shfl_xor(v, 16));
      v = fmaxf(v, __shfl_xor(v, 32));
      if (quad == 0)
        atomicMax((int*)obj + (size_t)n * 512 + col, __float_as_int(v));
    }
  }
}

// ======================= classifier layer 1 (1538 -> 1024), MFMA, barrier-free K-loop =======================
// grid = 1024 = 32 n * 8 octants * 4 row-quarters (25 px each), 3 blocks/CU.
// act tile (25 x 1024, stride 1032) staged ONCE; od-dot wave-cooperative & coalesced.
__global__ __launch_bounds__(256) void cls1_mfma_k(
    const f16* __restrict__ scnh, const float* __restrict__ obj,
    const float* __restrict__ pos, const float* __restrict__ w1raw,
    const f16* __restrict__ w1h, const float* __restrict__ b1,
    f16* __restrict__ h1h) {
  __shared__ f16 act[25 * 1032];           // 51,600 B
  __shared__ float odl[128], wAl[128], wBl[128];
  int b = blockIdx.x;
  int mq = b & 3, o8 = (b >> 2) & 7, n = b >> 5;
  int co0 = o8 * 128, p0 = mq * 25;
  int t = threadIdx.x, lane = t & 63, w = t >> 6;
  int quad = lane >> 4, l16 = lane & 15;
  // ---- stage full act tile (issue loads early) ----
  for (int i = t; i < 25 * 128; i += 256) {
    int row = i >> 7, c8 = i & 127;
    *(half8*)(act + row * 1032 + c8 * 8) =
        *(const half8*)(scnh + ((size_t)n * 100 + p0 + row) * 1024 + c8 * 8);
  }
  // ---- od dot: one co per wave-iteration; lane l covers k in [8l, 8l+8) ----
  {
    const float* ob = obj + (size_t)n * 512;
    for (int i = 0; i < 32; ++i) {
      int co = co0 + w * 32 + i;
      const float* wr = w1raw + (size_t)co * 1538 + 1024;
      float od = 0.0f;
#pragma unroll
      for (int j = 0; j < 4; ++j) {
        float2 wv = *(const float2*)(wr + lane * 8 + j * 2);
        float2 ov = *(const float2*)(ob + lane * 8 + j * 2);
        od = fmaf(wv.x, ov.x, od);
        od = fmaf(wv.y, ov.y, od);
      }
      od += __shfl_xor(od, 1);  od += __shfl_xor(od, 2);
      od += __shfl_xor(od, 4);  od += __shfl_xor(od, 8);
      od += __shfl_xor(od, 16); od += __shfl_xor(od, 32);
      if (lane == 0) {
        odl[w * 32 + i] = od + b1[co];
        wAl[w * 32 + i] = wr[512];
        wBl[w * 32 + i] = wr[513];
      }
    }
  }
  __syncthreads();
  float posx = pos[n * 2 + 0], posy = pos[n * 2 + 1];
  f32x4 acc[2][2];
#pragma unroll
  for (int mt = 0; mt < 2; ++mt)
#pragma unroll
    for (int nt = 0; nt < 2; ++nt) {
      int cl = w * 32 + nt * 16 + l16;
      float od = odl[cl], wA = wAl[cl], wB = wBl[cl];
#pragma unroll
      for (int r = 0; r < 4; ++r) {
        int pl = mt * 16 + quad * 4 + r;
        int px = p0 + (pl < 25 ? pl : 24);         // clamped lanes never stored
        float relx = posx - (-0.5f + ((px / 10) + 0.5f) * 0.1f);
        float rely = posy - (-0.5f + ((px % 10) + 0.5f) * 0.1f);
        acc[mt][nt][r] = od + relx * wA + rely * wB;
      }
    }
  // ---- barrier-free K loop: act fully resident in LDS ----
  int gr0 = l16;                                  // row for mt=0
  int gr1 = (16 + l16 > 24) ? 24 : 16 + l16;      // clamped row for mt=1 (rows independent)
  const f16* wb0 = w1h + (size_t)(co0 + w * 32 + l16) * 1024 + quad * 8;
  const f16* wb1 = wb0 + (size_t)16 * 1024;
#pragma unroll 4
  for (int kq = 0; kq < 32; ++kq) {
    int k0 = kq * 32;
    half8 bf0 = *(const half8*)(wb0 + k0);
    half8 bf1 = *(const half8*)(wb1 + k0);
    half8 a0 = *(const half8*)(act + gr0 * 1032 + k0 + quad * 8);
    half8 a1 = *(const half8*)(act + gr1 * 1032 + k0 + quad * 8);
    acc[0][0] = MFMA16(a0, bf0, acc[0][0]);
    acc[1][0] = MFMA16(a1, bf0, acc[1][0]);
    acc[0][1] = MFMA16(a0, bf1, acc[0][1]);
    acc[1][1] = MFMA16(a1, bf1, acc[1][1]);
  }
#pragma unroll
  for (int mt = 0; mt < 2; ++mt)
#pragma unroll
    for (int nt = 0; nt < 2; ++nt) {
      int co = co0 + w * 32 + nt * 16 + l16;
#pragma unroll
      for (int r = 0; r < 4; ++r) {
        int pl = mt * 16 + quad * 4 + r;
        if (pl < 25)
          h1h[((size_t)n * 100 + p0 + pl) * 1024 + co] = (f16)fmaxf(acc[mt][nt][r], 0.0f);
      }
    }
}

// ======================= classifier layer 2 (1024 -> 256), MFMA =======================
__global__ __launch_bounds__(256) void cls2_mfma_k(
    const f16* __restrict__ h1h, const f16* __restrict__ w2h16,
    const float* __restrict__ b2, f16* __restrict__ h2h) {
  __shared__ f16 act[64 * 72];
  int b = blockIdx.x;
  int ng = b & 1, mh = (b >> 1) & 1, n = b >> 2;
  int co0 = ng * 128, p0 = mh * 50;
  int t = threadIdx.x, lane = t & 63, w = t >> 6;
  int quad = lane >> 4, l16 = lane & 15;
  f32x4 acc[4][2] = {};
  for (int kc = 0; kc < 16; ++kc) {
    int k0 = kc * 64;
    __syncthreads();
    for (int i = t; i < 512; i += 256) {
      int row = i >> 3, c8 = i & 7;                // rows 0..63
      int gr = p0 + (row < 50 ? row : 49);         // clamp; garbage rows never stored
      *(half8*)(act + row * 72 + c8 * 8) =
          *(const half8*)(h1h + ((size_t)n * 100 + gr) * 1024 + k0 + c8 * 8);
    }
    __syncthreads();
#pragma unroll
    for (int ks = 0; ks < 2; ++ks) {
      half8 bf0 = *(const half8*)(w2h16 + (size_t)(co0 + w * 32 + l16) * 1024 + k0 + ks * 32 + quad * 8);
      half8 bf1 = *(const half8*)(w2h16 + (size_t)(co0 + w * 32 + 16 + l16) * 1024 + k0 + ks * 32 + quad * 8);
#pragma unroll
      for (int mt = 0; mt < 4; ++mt) {
        half8 a = *(const half8*)(act + (mt * 16 + l16) * 72 + ks * 32 + quad * 8);
        acc[mt][0] = MFMA16(a, bf0, acc[mt][0]);
        acc[mt][1] = MFMA16(a, bf1, acc[mt][1]);
      }
    }
  }
#pragma unroll
  for (int mt = 0; mt < 4; ++mt)
#pragma unroll
    for (int nt = 0; nt < 2; ++nt) {
      int co = co0 + w * 32 + nt * 16 + l16;
      float bb = b2[co];
#pragma unroll
      for (int r = 0; r < 4; ++r) {
        int pl = mt * 16 + quad * 4 + r;
        if (pl < 50)
          h2h[((size_t)n * 100 + p0 + pl) * 256 + co] = (f16)fmaxf(acc[mt][nt][r] + bb, 0.0f);
      }
    }
}

// ======================= classifier layer 3 (256 -> 1) =======================
__global__ void cls3_k(const f16* __restrict__ h2h, const float* __restrict__ w3,
                       const float* __restrict__ b3, float* __restrict__ out) {
  int n = blockIdx.x, t = threadIdx.x;
  if (t < 100) {
    float acc = b3[0];
    const f16* hp = &h2h[((size_t)n * 100 + t) * 256];
    for (int k = 0; k < 256; ++k) acc = fmaf((float)hp[k], w3[k], acc);
    out[n * 100 + t] = acc;
  }
}

// ======================= launch =======================
extern "C" void kernel_launch(void* const* d_in, const int* in_sizes, int n_in,
                              void* d_out, int out_size, void* d_ws, size_t ws_size,
                              hipStream_t stream) {
  const float* sc      = (const float*)d_in[0];
  const float* oc      = (const float*)d_in[1];
  const float* pos     = (const float*)d_in[2];
  const float* mlp_w1  = (const float*)d_in[3];
  const float* mlp_b1  = (const float*)d_in[4];
  const float* mlp_w2  = (const float*)d_in[5];
  const float* mlp_b2  = (const float*)d_in[6];
  const float* conv1_w = (const float*)d_in[7];
  const float* conv1_b = (const float*)d_in[8];
  const float* conv2_w = (const float*)d_in[9];
  const float* conv2_b = (const float*)d_in[10];
  const float* convt_w = (const float*)d_in[11];
  const float* convt_b = (const float*)d_in[12];
  const float* sa_w1   = (const float*)d_in[13];
  const float* sa_b1   = (const float*)d_in[14];
  const float* sa_w2   = (const float*)d_in[15];
  const float* sa_b2   = (const float*)d_in[16];
  const float* sa_w3   = (const float*)d_in[17];
  const float* sa_b3   = (const float*)d_in[18];
  const float* sa_w4   = (const float*)d_in[19];
  const float* sa_b4   = (const float*)d_in[20];
  const float* cls_w1  = (const float*)d_in[21];
  const float* cls_b1  = (const float*)d_in[22];
  const float* cls_w2  = (const float*)d_in[23];
  const float* cls_b2  = (const float*)d_in[24];
  const float* cls_w3  = (const float*)d_in[25];
  const float* cls_b3  = (const float*)d_in[26];

  float* ws = (float*)d_ws;
  // ---- workspace layout (float units) ----
  f16*   w1h   = (f16*)ws;                         // 589,824 f (conv1 B-frag)
  f16*   w2h   = (f16*)(ws + 589824);              // 2,359,296 f (conv2 B-frag; reused: h1h)
  f16*   mw2h  = (f16*)(ws + 2949120);             // 16,384 f
  f16*   saw2h = (f16*)(ws + 2965504);             // 4,096 f
  f16*   saw3h = (f16*)(ws + 2969600);             // 16,384 f
  f16*   saw4h = (f16*)(ws + 2985984);             // 65,536 f
  f16*   cw1h  = (f16*)(ws + 3051520);             // 524,288 f
  f16*   ctwh  = (f16*)(ws + 3575808);             // 1,048,576 f (B-frag layout)
  f16*   cw2h  = (f16*)(ws + 4624384);             // 131,072 f ([256][1024] fp16)
  float* big   = ws + 4886528;                     // 3,276,800 f (voxg, g1buf, g2buf)
  f16*   voxh  = (f16*)(ws + 8163328);             // 819,200 f (reused: f2h)
  f16*   f1h   = (f16*)(ws + 8982528);             // 819,200 f
  f16*   scnh  = (f16*)(ws + 9801728);             // 1,638,400 f (reused: h2h)
  float* obj   = ws + 11440128;                    // 16,384 f
  float* ocm   = ws + 11456512;                    // 64 f

  float* voxg  = big;                              // fp32 voxel merge buffer [32][400][256]
  f16*   g1buf = (f16*)big;                        // conv1 out (voxg dead after pack)
  f16*   g2buf = (f16*)big;                        // conv2 out (g1buf dead after pool1)
  f16*   f2h   = voxh;                             // pool2 out (voxh dead after conv1)
  f16*   h1h   = w2h;                              // cls1 out (w2h dead after conv2)
  f16*   h2h   = scnh;                             // cls2 out (scnh dead after cls1)
  float* outp  = (float*)d_out;

  // ---- weight preps ----
  wfragprep_k<512, 256><<<512, 256, 0, stream>>>(conv1_w, w1h);
  wfragprep_k<1024, 512><<<1024, 256, 0, stream>>>(conv2_w, w2h);
  cvt16_k<<<32, 256, 0, stream>>>(mlp_w2, mw2h, 8192);
  cvt16_k<<<8, 256, 0, stream>>>(sa_w2, saw2h, 2048);
  cvt16_k<<<32, 256, 0, stream>>>(sa_w3, saw3h, 8192);
  cvt16_k<<<128, 256, 0, stream>>>(sa_w4, saw4h, 32768);
  cw1prep_k<<<4096, 256, 0, stream>>>(cls_w1, cw1h);
  ctprep_k<<<8192, 256, 0, stream>>>(convt_w, ctwh);
  cvt16_k<<<256, 256, 0, stream>>>(cls_w2, cw2h, 65536);

  hipMemsetAsync(obj, 0, (size_t)16384 * 4, stream);
  hipMemsetAsync(voxg, 0, (size_t)3276800 * 4, stream);
  ocmean_k<<<32, 256, 0, stream>>>(oc, ocm);

  pointnet_lds_k<<<1024, 256, 0, stream>>>(sc, mlp_w1, mlp_b1, mw2h, mlp_b2, voxg);
  cvt16_k<<<3200, 256, 0, stream>>>(voxg, voxh, 819200);

  convmfma_k<20, 20, 256, 512, 4><<<512, 256, 7 * 22 * 80, stream>>>(
      voxh, w1h, conv1_b, g1buf);
  pool1_k<<<3200, 256, 0, stream>>>(g1buf, f1h, scnh);
  convmfma_k<10, 10, 512, 1024, 2><<<512, 256, 7 * 12 * 80, stream>>>(
      f1h, w2h, conv2_b, g2buf);
  pool2_k<<<1600, 256, 0, stream>>>(g2buf, f2h);
  convt_mfma_k<<<512, 256, 0, stream>>>(f2h, ctwh, convt_b, scnh);

  sa_mfma_k<<<1024, 256, 0, stream>>>(oc, ocm, sa_w1, sa_b1, saw2h, sa_b2,
                                      saw3h, sa_b3, saw4h, sa_b4, obj);

  cls1_mfma_k<<<1024, 256, 0, stream>>>(scnh, obj, pos, cls_w1, cw1h, cls_b1, h1h);
  cls2_mfma_k<<<128, 256, 0, stream>>>(h1h, cw2h, cls_b2, h2h);
  cls3_k<<<32, 128, 0, stream>>>(h2h, cls_w3, cls_b3, outp);
}

// Round 6
// 497.748 us; speedup vs baseline: 1.0554x; 1.0554x over previous
//
#include <hip/hip_runtime.h>

#define NB 32
#define PP 8192
#define OPP 2048

typedef _Float16 f16;
typedef f16 half8 __attribute__((ext_vector_type(8)));
typedef f16 half4 __attribute__((ext_vector_type(4)));
typedef f16 half2v __attribute__((ext_vector_type(2)));
typedef float f32x4 __attribute__((ext_vector_type(4)));

#define MFMA16(a, b, c) __builtin_amdgcn_mfma_f32_16x16x32_f16(a, b, c, 0, 0, 0)

// ======= conv weight prep: [co][ci][3][3] fp32 -> MFMA B-fragment order fp16 =======
template <int CO, int CI>
__global__ __launch_bounds__(256) void wfragprep_k(const float* __restrict__ wsrc,
                                                   f16* __restrict__ wf) {
  __shared__ float tile[CI * 9];
  int co = blockIdx.x, t = threadIdx.x;
  const float* src = wsrc + (size_t)co * CI * 9;
  for (int i = t; i < CI * 9; i += 256) tile[i] = src[i];
  __syncthreads();
  constexpr int NBB = CO / 16;
  int nb = co >> 4, l16 = co & 15;
  for (int e = t; e < (CI / 32) * 9 * 4; e += 256) {
    int quad = e & 3;
    int kk = (e >> 2) % 9;
    int cic = e / 36;
    half8 v;
#pragma unroll
    for (int j = 0; j < 8; ++j) {
      int ci = cic * 32 + quad * 8 + j;
      v[j] = (f16)tile[ci * 9 + kk];
    }
    *(half8*)(wf + ((((size_t)cic * 9 + kk) * NBB + nb) * 64 + quad * 16 + l16) * 8) = v;
  }
}

__global__ void cvt16_k(const float* __restrict__ in, f16* __restrict__ out, int n4) {
  int idx = blockIdx.x * 256 + threadIdx.x;
  if (idx >= n4) return;
  float4 v = ((const float4*)in)[idx];
  half4 h; h.x = (f16)v.x; h.y = (f16)v.y; h.z = (f16)v.z; h.w = (f16)v.w;
  ((half4*)out)[idx] = h;
}

// cls_w1 scene part [1024][1538] -> [1024][1024] fp16
__global__ void cw1prep_k(const float* __restrict__ w, f16* __restrict__ out) {
  int idx = blockIdx.x * 256 + threadIdx.x;
  if (idx >= 1024 * 1024) return;
  int co = idx >> 10, k = idx & 1023;
  out[idx] = (f16)w[(size_t)co * 1538 + k];
}

// convt_w [o][i][a'][b'] -> MFMA B-fragment layout
__global__ void ctprep_k(const float* __restrict__ w, f16* __restrict__ out) {
  int idx = blockIdx.x * 256 + threadIdx.x;
  if (idx >= 2048 * 1024) return;
  int j = idx & 7, l = (idx >> 3) & 63, kb = (idx >> 9) & 31, nb = idx >> 14;
  int n16 = l & 15, quad = l >> 4;
  int np = nb * 16 + n16;
  int k = kb * 32 + quad * 8 + j;
  int p = np >> 9, o = np & 511;
  out[idx] = (f16)w[((size_t)o * 1024 + k) * 4 + (3 - p)];
}

// ======================= object-cloud mean =======================
__global__ void ocmean_k(const float* __restrict__ oc, float* __restrict__ ocm) {
  int n = blockIdx.x, t = threadIdx.x;
  __shared__ float sx[256], sy[256];
  float ax = 0.f, ay = 0.f;
  for (int p = t; p < OPP; p += 256) {
    ax += oc[((size_t)n * OPP + p) * 2 + 0];
    ay += oc[((size_t)n * OPP + p) * 2 + 1];
  }
  sx[t] = ax; sy[t] = ay;
  __syncthreads();
  for (int s = 128; s > 0; s >>= 1) {
    if (t < s) { sx[t] += sx[t + s]; sy[t] += sy[t + s]; }
    __syncthreads();
  }
  if (t == 0) {
    ocm[n * 2 + 0] = sx[0] / (float)OPP;
    ocm[n * 2 + 1] = sy[0] / (float)OPP;
  }
}

// ======================= voxel PointNet: barrier-free LDS scatter-max =======================
__global__ __launch_bounds__(256) void pointnet_lds_k(
    const float* __restrict__ sc, const float* __restrict__ w1, const float* __restrict__ b1,
    const f16* __restrict__ w2h, const float* __restrict__ b2, float* __restrict__ voxg) {
  __shared__ float voxl[400 * 33];         // 52,800 B
  int t = threadIdx.x, lane = t & 63, w = t >> 6;
  int quad = lane >> 4, l16 = lane & 15;
  int b = blockIdx.x;
  int ps = b & 3, cg = (b >> 2) & 7, n = b >> 5;
  // packed layer-1 weights: this quad's 32 channels => 16 half2 per array
  half2v w1x2[16], w1y2[16], b12[16];
#pragma unroll
  for (int i = 0; i < 16; ++i) {
    int k0 = (i >> 2) * 32 + quad * 8 + (i & 3) * 2;   // ks = i>>2, j2 = i&3
    w1x2[i] = (half2v){(f16)w1[k0 * 2], (f16)w1[(k0 + 1) * 2]};
    w1y2[i] = (half2v){(f16)w1[k0 * 2 + 1], (f16)w1[(k0 + 1) * 2 + 1]};
    b12[i]  = (half2v){(f16)b1[k0], (f16)b1[k0 + 1]};
  }
  half8 bf[2][4];
  float bias[2];
#pragma unroll
  for (int nt = 0; nt < 2; ++nt) {
    int ch = cg * 32 + nt * 16 + l16;
    bias[nt] = b2[ch];
#pragma unroll
    for (int ks = 0; ks < 4; ++ks)
      bf[nt][ks] = *(const half8*)(w2h + (size_t)ch * 128 + ks * 32 + quad * 8);
  }
  for (int i = t; i < 400 * 33; i += 256) voxl[i] = 0.0f;
  __syncthreads();
  const half2v z2 = {};
  const float* scp = sc + ((size_t)n * PP + (size_t)ps * 2048) * 2;
  int p0 = w * 16 + l16;
  float2 xy = *(const float2*)(scp + p0 * 2);
  for (int it = 0; it < 32; ++it) {
    float x = xy.x, y = xy.y;
    if (it < 31) xy = *(const float2*)(scp + ((it + 1) * 64 + p0) * 2);
    float bif = fminf(fmaxf(ceilf((x + 0.5f) * 20.0f) - 1.0f, 0.0f), 19.0f);
    float bjf = fminf(fmaxf(ceilf((y + 0.5f) * 20.0f) - 1.0f, 0.0f), 19.0f);
    bool valid = (x > -0.5f) && (x <= 0.5f) && (y > -0.5f) && (y <= 0.5f);
    float px = x - (-0.5f + (bif + 0.5f) * 0.05f);
    float py = y - (-0.5f + (bjf + 0.5f) * 0.05f);
    int bn = valid ? ((int)bif * 20 + (int)bjf) : -1;
    f16 pxh = (f16)px, pyh = (f16)py;
    half2v px2 = (half2v){pxh, pxh}, py2 = (half2v){pyh, pyh};
    f32x4 acc0 = {}, acc1 = {};
#pragma unroll
    for (int ks = 0; ks < 4; ++ks) {
      half8 af;
#pragma unroll
      for (int j2 = 0; j2 < 4; ++j2) {
        half2v tmp = w1x2[ks * 4 + j2] * px2 + (w1y2[ks * 4 + j2] * py2 + b12[ks * 4 + j2]);
        tmp = __builtin_elementwise_max(tmp, z2);
        reinterpret_cast<half2v*>(&af)[j2] = tmp;
      }
      acc0 = MFMA16(af, bf[0][ks], acc0);
      acc1 = MFMA16(af, bf[1][ks], acc1);
    }
#pragma unroll
    for (int r = 0; r < 4; ++r) {
      int bn2 = __shfl(bn, quad * 4 + r);
      if (bn2 >= 0) {
        float v0 = fmaxf(acc0[r] + bias[0], 0.0f);
        float v1 = fmaxf(acc1[r] + bias[1], 0.0f);
        atomicMax((int*)voxl + bn2 * 33 + l16, __float_as_int(v0));
        atomicMax((int*)voxl + bn2 * 33 + 16 + l16, __float_as_int(v1));
      }
    }
  }
  __syncthreads();
  // merge private LDS grid into the global fp32 voxel buffer
  float* vg = voxg + ((size_t)n * 400) * 256 + cg * 32;
  for (int i = t; i < 400 * 32; i += 256) {
    int bin = i >> 5, c = i & 31;
    float v = voxl[bin * 33 + c];
    if (v > 0.0f)
      atomicMax((int*)(vg + (size_t)bin * 256) + c, __float_as_int(v));
  }
}

// ======================= MFMA implicit-GEMM conv 3x3 pad1 + relu =======================
template <int H, int W, int CI, int CO, int MSPLIT>
__global__ __launch_bounds__(256, 2) void convmfma_k(
    const f16* __restrict__ inh, const f16* __restrict__ wf,
    const float* __restrict__ bias, f16* __restrict__ outh) {
  constexpr int HS = H / MSPLIT;
  constexpr int Mpix = HS * W;
  constexpr int MT = (Mpix + 15) / 16;
  constexpr int PR = HS + 2, PC = W + 2;
  constexpr int NCIC = CI / 32;
  constexpr int COG = CO / 128;
  constexpr int NBB = CO / 16;
  extern __shared__ char smem[];
  f16* Ap = (f16*)smem;                          // [PR*PC][40]
  int b = blockIdx.x;
  int cog = b % COG;
  int ms = (b / COG) % MSPLIT;
  int n = b / (COG * MSPLIT);
  int co0 = cog * 128;
  int r0 = ms * HS;
  int t = threadIdx.x, lane = t & 63, w = t >> 6;
  int quad = lane >> 4, l16 = lane & 15;
  int nb0 = cog * 8 + w * 2;                     // B-fragment row-block (16 co each)

  int abase[MT];
#pragma unroll
  for (int mi = 0; mi < MT; ++mi) {
    int pl = mi * 16 + l16; if (pl > Mpix - 1) pl = Mpix - 1;
    int y = pl / W, x = pl - y * W;
    abase[mi] = (y * PC + x) * 40 + quad * 8;    // halves
  }
  f32x4 acc[MT][2] = {};

  const f16* inbase = inh + (size_t)n * H * W * CI;

  for (int cic = 0; cic < NCIC; ++cic) {
    __syncthreads();                             // protect Ap from prior reads
    for (int cell = t; cell < PR * PC; cell += 256) {
      int pr = cell / PC, pc = cell - pr * PC;
      int yin = r0 - 1 + pr, xin = pc - 1;
      uint4 d0 = {0,0,0,0}, d1 = {0,0,0,0}, d2 = {0,0,0,0}, d3 = {0,0,0,0};
      if (yin >= 0 && yin < H && xin >= 0 && xin < W) {
        const uint4* src = (const uint4*)(inbase + ((size_t)yin * W + xin) * CI + cic * 32);
        d0 = src[0]; d1 = src[1]; d2 = src[2]; d3 = src[3];
      }
      uint4* dst = (uint4*)(Ap + cell * 40);
      dst[0] = d0; dst[1] = d1; dst[2] = d2; dst[3] = d3;
    }
    __syncthreads();
    const f16* wfc = wf + (size_t)(cic * 9) * NBB * 512;
#pragma unroll
    for (int ky = 0; ky < 3; ++ky)
#pragma unroll
      for (int kx = 0; kx < 3; ++kx) {
        int kk = ky * 3 + kx;
        half8 bf0 = *(const half8*)(wfc + ((size_t)(kk * NBB + nb0) * 64 + lane) * 8);
        half8 bf1 = *(const half8*)(wfc + ((size_t)(kk * NBB + nb0 + 1) * 64 + lane) * 8);
        int shift = (ky * PC + kx) * 40;
#pragma unroll
        for (int mi = 0; mi < MT; ++mi) {
          half8 af = *(const half8*)(Ap + abase[mi] + shift);
          acc[mi][0] = MFMA16(af, bf0, acc[mi][0]);
          acc[mi][1] = MFMA16(af, bf1, acc[mi][1]);
        }
      }
  }
  int co_w = co0 + w * 32;
  float bv0 = bias[co_w + l16];
  float bv1 = bias[co_w + 16 + l16];
  f16* ob = outh + ((size_t)n * H * W + (size_t)ms * Mpix) * CO;
#pragma unroll
  for (int mi = 0; mi < MT; ++mi) {
#pragma unroll
    for (int r = 0; r < 4; ++r) {
      int p = mi * 16 + quad * 4 + r;
      if (p < Mpix) {
        float v0 = acc[mi][0][r] + bv0; v0 = v0 > 0.f ? v0 : 0.f;
        float v1 = acc[mi][1][r] + bv1; v1 = v1 > 0.f ? v1 : 0.f;
        ob[(size_t)p * CO + co_w + l16] = (f16)v0;
        ob[(size_t)p * CO + co_w + 16 + l16] = (f16)v1;
      }
    }
  }
}

// ======================= maxpool 2x2 (+ fused pack into scene buffer) =======================
__global__ void pool1_k(const f16* __restrict__ g1, f16* __restrict__ f1h,
                        f16* __restrict__ scnh) {
  int idx = blockIdx.x * 256 + threadIdx.x;
  if (idx >= 32 * 100 * 256) return;
  int c2 = idx & 255, rem = idx >> 8;
  int op = rem % 100, n = rem / 100;
  int py = op / 10, px = op - py * 10;
  const f16* base = g1 + (((size_t)n * 400 + (size_t)(2 * py) * 20 + 2 * px) * 512) + c2 * 2;
  float a0 = (float)base[0],   a1 = (float)base[1];
  float b0 = (float)base[512], b1 = (float)base[513];
  const f16* base2 = base + 20 * 512;
  float c0 = (float)base2[0],   c1 = (float)base2[1];
  float d0 = (float)base2[512], d1 = (float)base2[513];
  union { f16 h[2]; unsigned u; } pk;
  pk.h[0] = (f16)fmaxf(fmaxf(a0, b0), fmaxf(c0, d0));
  pk.h[1] = (f16)fmaxf(fmaxf(a1, b1), fmaxf(c1, d1));
  *(unsigned*)(f1h + ((size_t)n * 100 + op) * 512 + c2 * 2) = pk.u;
  *(unsigned*)(scnh + ((size_t)n * 100 + op) * 1024 + c2 * 2) = pk.u;
}

__global__ void pool2_k(const f16* __restrict__ g2, f16* __restrict__ f2h) {
  int idx = blockIdx.x * 256 + threadIdx.x;
  if (idx >= 32 * 25 * 512) return;
  int c2 = idx & 511, rem = idx >> 9;
  int op = rem % 25, n = rem / 25;
  int py = op / 5, px = op - py * 5;
  const f16* base = g2 + (((size_t)n * 100 + (size_t)(2 * py) * 10 + 2 * px) * 1024) + c2 * 2;
  float a0 = (float)base[0],    a1 = (float)base[1];
  float b0 = (float)base[1024], b1 = (float)base[1025];
  const f16* base2 = base + 10 * 1024;
  float c0 = (float)base2[0],    c1 = (float)base2[1];
  float d0 = (float)base2[1024], d1 = (float)base2[1025];
  f16* o = f2h + ((size_t)n * 25 + op) * 1024 + c2 * 2;
  o[0] = (f16)fmaxf(fmaxf(a0, b0), fmaxf(c0, d0));
  o[1] = (f16)fmaxf(fmaxf(a1, b1), fmaxf(c1, d1));
}

// ======================= conv transpose 2x2 s2 (1024->512), MFMA v2 =======================
__global__ __launch_bounds__(256, 2) void convt_mfma_k(
    const f16* __restrict__ f2h, const f16* __restrict__ ctwf,
    const float* __restrict__ ctb, f16* __restrict__ scnh) {
  __shared__ f16 act[25 * 1048];           // 52,400 B
  int b = blockIdx.x;
  int ng = b & 15, n = b >> 4;
  int t = threadIdx.x, lane = t & 63, w = t >> 6;
  int quad = lane >> 4, l16 = lane & 15;
  for (int i = t; i < 25 * 128; i += 256) {
    int row = i >> 7, c8 = i & 127;
    *(half8*)(act + row * 1048 + c8 * 8) =
        *(const half8*)(f2h + ((size_t)n * 25 + row) * 1024 + c8 * 8);
  }
  __syncthreads();
  int r1 = 16 + (l16 > 8 ? 8 : l16);       // clamp: garbage rows never stored
  f32x4 acc[2][2] = {};
  const f16* wp0 = ctwf + ((size_t)((ng * 8 + w * 2 + 0) * 32) * 64 + lane) * 8;
  const f16* wp1 = ctwf + ((size_t)((ng * 8 + w * 2 + 1) * 32) * 64 + lane) * 8;
#pragma unroll 4
  for (int ks = 0; ks < 32; ++ks) {
    half8 a0 = *(const half8*)(act + l16 * 1048 + ks * 32 + quad * 8);
    half8 a1 = *(const half8*)(act + r1 * 1048 + ks * 32 + quad * 8);
    half8 b0 = *(const half8*)(wp0 + (size_t)ks * 512);
    half8 b1 = *(const half8*)(wp1 + (size_t)ks * 512);
    acc[0][0] = MFMA16(a0, b0, acc[0][0]);
    acc[1][0] = MFMA16(a1, b0, acc[1][0]);
    acc[0][1] = MFMA16(a0, b1, acc[0][1]);
    acc[1][1] = MFMA16(a1, b1, acc[1][1]);
  }
#pragma unroll
  for (int nt = 0; nt < 2; ++nt) {
    int np = ng * 128 + w * 32 + nt * 16 + l16;
    int p = np >> 9, co = np & 511;
    int a = p >> 1, bc = p & 1;
    float bb = ctb[co];
#pragma unroll
    for (int mt = 0; mt < 2; ++mt)
#pragma unroll
      for (int r = 0; r < 4; ++r) {
        int px = mt * 16 + quad * 4 + r;
        if (px < 25) {
          int ph = px / 5, pw = px - ph * 5;
          int opx = (2 * ph + a) * 10 + 2 * pw + bc;
          scnh[((size_t)n * 100 + opx) * 1024 + 512 + co] = (f16)(acc[mt][nt][r] + bb);
        }
      }
  }
}

// ======================= object SA: fused 4-layer MFMA + max (M=64 tiles) =======================
__global__ __launch_bounds__(256, 2) void sa_mfma_k(
    const float* __restrict__ oc, const float* __restrict__ ocm,
    const float* __restrict__ w1, const float* __restrict__ b1,
    const f16* __restrict__ w2h, const float* __restrict__ b2,
    const f16* __restrict__ w3h, const float* __restrict__ b3,
    const f16* __restrict__ w4h, const float* __restrict__ b4,
    float* __restrict__ obj) {
  __shared__ f16 act1[64 * 72];            // 9,216 B [pt][K=64]
  __shared__ f16 act2[64 * 136];           // 17,408 B [pt][K=128]
  __shared__ f16 act3[64 * 264];           // 33,792 B [pt][K=256]
  __shared__ float pcx[64], pcy[64];
  int b = blockIdx.x;                      // 1024 = 32 n * 32 chunks of 64 pts
  int n = b >> 5, pb = (b & 31) * 64;
  int t = threadIdx.x, lane = t & 63, w = t >> 6;
  int quad = lane >> 4, l16 = lane & 15;
  if (t < 64) {
    pcx[t] = oc[((size_t)n * OPP + pb + t) * 2 + 0] - ocm[n * 2 + 0];
    pcy[t] = oc[((size_t)n * OPP + pb + t) * 2 + 1] - ocm[n * 2 + 1];
  }
  __syncthreads();
  {                                        // layer1: 2 -> 64 for 64 points
    int c = t & 63, pg = t >> 6;
    float wx = w1[c * 2], wy = w1[c * 2 + 1], bb = b1[c];
#pragma unroll
    for (int j = 0; j < 16; ++j) {
      int p = pg * 16 + j;
      act1[p * 72 + c] = (f16)fmaxf(fmaf(wx, pcx[p], fmaf(wy, pcy[p], bb)), 0.0f);
    }
  }
  __syncthreads();
  {                                        // layer2: M=64, K=64, N=128; wave n-range 32
    int n0 = w * 32;
    f32x4 acc[4][2] = {};
#pragma unroll
    for (int ks = 0; ks < 2; ++ks) {
      half8 a[4];
#pragma unroll
      for (int mt = 0; mt < 4; ++mt)
        a[mt] = *(const half8*)(act1 + (mt * 16 + l16) * 72 + ks * 32 + quad * 8);
#pragma unroll
      for (int nt = 0; nt < 2; ++nt) {
        half8 bf = *(const half8*)(w2h + (size_t)(n0 + nt * 16 + l16) * 64 + ks * 32 + quad * 8);
#pragma unroll
        for (int mt = 0; mt < 4; ++mt)
          acc[mt][nt] = MFMA16(a[mt], bf, acc[mt][nt]);
      }
    }
#pragma unroll
    for (int nt = 0; nt < 2; ++nt) {
      int col = n0 + nt * 16 + l16;
      float bb = b2[col];
#pragma unroll
      for (int mt = 0; mt < 4; ++mt)
#pragma unroll
        for (int r = 0; r < 4; ++r)
          act2[(mt * 16 + quad * 4 + r) * 136 + col] = (f16)fmaxf(acc[mt][nt][r] + bb, 0.0f);
    }
  }
  __syncthreads();
  {                                        // layer3: M=64, K=128, N=256; wave n-range 64
    int n0 = w * 64;
    f32x4 acc[4][4] = {};
#pragma unroll
    for (int ks = 0; ks < 4; ++ks) {
      half8 a[4];
#pragma unroll
      for (int mt = 0; mt < 4; ++mt)
        a[mt] = *(const half8*)(act2 + (mt * 16 + l16) * 136 + ks * 32 + quad * 8);
#pragma unroll
      for (int nt = 0; nt < 4; ++nt) {
        half8 bf = *(const half8*)(w3h + (size_t)(n0 + nt * 16 + l16) * 128 + ks * 32 + quad * 8);
#pragma unroll
        for (int mt = 0; mt < 4; ++mt)
          acc[mt][nt] = MFMA16(a[mt], bf, acc[mt][nt]);
      }
    }
#pragma unroll
    for (int nt = 0; nt < 4; ++nt) {
      int col = n0 + nt * 16 + l16;
      float bb = b3[col];
#pragma unroll
      for (int mt = 0; mt < 4; ++mt)
#pragma unroll
        for (int r = 0; r < 4; ++r)
          act3[(mt * 16 + quad * 4 + r) * 264 + col] = (f16)fmaxf(acc[mt][nt][r] + bb, 0.0f);
    }
  }
  __syncthreads();
  {                                        // layer4: M=64, K=256, N=512; wave n-range 128; + max
    int n0 = w * 128;
    f32x4 acc[4][8] = {};
#pragma unroll
    for (int ks = 0; ks < 8; ++ks) {
      half8 a[4];
#pragma unroll
      for (int mt = 0; mt < 4; ++mt)
        a[mt] = *(const half8*)(act3 + (mt * 16 + l16) * 264 + ks * 32 + quad * 8);
#pragma unroll
      for (int nt = 0; nt < 8; ++nt) {
        half8 bf = *(const half8*)(w4h + (size_t)(n0 + nt * 16 + l16) * 256 + ks * 32 + quad * 8);
#pragma unroll
        for (int mt = 0; mt < 4; ++mt)
          acc[mt][nt] = MFMA16(a[mt], bf, acc[mt][nt]);
      }
    }
#pragma unroll
    for (int nt = 0; nt < 8; ++nt) {
      int col = n0 + nt * 16 + l16;
      float bb = b4[col];
      float v = 0.0f;
#pragma unroll
      for (int mt = 0; mt < 4; ++mt)
#pragma unroll
        for (int r = 0; r < 4; ++r)
          v = fmaxf(v, acc[mt][nt][r] + bb);
      v = fmaxf(v, 0.0f);
      v = fmaxf(v, __shfl_xor(v, 16));
      v = fmaxf(v, __shfl_xor(v, 32));
      if (quad == 0)
        atomicMax((int*)obj + (size_t)n * 512 + col, __float_as_int(v));
    }
  }
}

// ======================= obj-dot precompute: odw[n][co] = obj[n]·w1raw[co,1024:1536] + b1 =======
// grid = 1024 (one co per block); w1raw obj-part read once total (vs 262 MB before).
__global__ __launch_bounds__(256) void odprep_k(
    const float* __restrict__ obj, const float* __restrict__ w1raw,
    const float* __restrict__ b1, float* __restrict__ odw, float* __restrict__ wab) {
  int co = blockIdx.x;
  int t = threadIdx.x, lane = t & 63, w = t >> 6;
  const float* wr = w1raw + (size_t)co * 1538 + 1024;
  // hoist this co's weights: lane covers k in [8*lane, 8*lane+8)  (float2: 8B-aligned safe)
  float2 wv[4];
#pragma unroll
  for (int j = 0; j < 4; ++j) wv[j] = *(const float2*)(wr + lane * 8 + j * 2);
  float bb = b1[co];
  for (int i = 0; i < 8; ++i) {
    int n = w * 8 + i;
    const float* ob = obj + (size_t)n * 512 + lane * 8;
    float od = 0.0f;
#pragma unroll
    for (int j = 0; j < 4; ++j) {
      float2 ov = *(const float2*)(ob + j * 2);
      od = fmaf(wv[j].x, ov.x, od);
      od = fmaf(wv[j].y, ov.y, od);
    }
    od += __shfl_xor(od, 1);  od += __shfl_xor(od, 2);
    od += __shfl_xor(od, 4);  od += __shfl_xor(od, 8);
    od += __shfl_xor(od, 16); od += __shfl_xor(od, 32);
    if (lane == 0) odw[(size_t)n * 1024 + co] = od + bb;
  }
  if (t == 0) { wab[co * 2] = wr[512]; wab[co * 2 + 1] = wr[513]; }
}

// ======================= classifier layer 1 (1538 -> 1024), MFMA =======================
// grid = 1024; bit layout o8 = b&7 so all blocks sharing a w1h octant slice land on ONE XCD
// (round-robin %8) -> B-fragment re-reads are L2 hits, not Infinity-Cache traffic.
__global__ __launch_bounds__(256) void cls1_mfma_k(
    const f16* __restrict__ scnh, const float* __restrict__ odw,
    const float* __restrict__ wab, const float* __restrict__ pos,
    const f16* __restrict__ w1h, f16* __restrict__ h1h) {
  __shared__ f16 act[25 * 1032];           // 51,600 B
  __shared__ float odl[128], wAl[128], wBl[128];
  int b = blockIdx.x;
  int o8 = b & 7, mq = (b >> 3) & 3, n = b >> 5;
  int co0 = o8 * 128, p0 = mq * 25;
  int t = threadIdx.x, lane = t & 63, w = t >> 6;
  int quad = lane >> 4, l16 = lane & 15;
  // ---- stage full act tile ----
  for (int i = t; i < 25 * 128; i += 256) {
    int row = i >> 7, c8 = i & 127;
    *(half8*)(act + row * 1032 + c8 * 8) =
        *(const half8*)(scnh + ((size_t)n * 100 + p0 + row) * 1024 + c8 * 8);
  }
  if (t < 128) {
    odl[t] = odw[(size_t)n * 1024 + co0 + t];
    float2 ab = *(const float2*)(wab + (size_t)(co0 + t) * 2);
    wAl[t] = ab.x; wBl[t] = ab.y;
  }
  __syncthreads();
  float posx = pos[n * 2 + 0], posy = pos[n * 2 + 1];
  f32x4 acc[2][2];
#pragma unroll
  for (int mt = 0; mt < 2; ++mt)
#pragma unroll
    for (int nt = 0; nt < 2; ++nt) {
      int cl = w * 32 + nt * 16 + l16;
      float od = odl[cl], wA = wAl[cl], wB = wBl[cl];
#pragma unroll
      for (int r = 0; r < 4; ++r) {
        int pl = mt * 16 + quad * 4 + r;
        int px = p0 + (pl < 25 ? pl : 24);         // clamped lanes never stored
        float relx = posx - (-0.5f + ((px / 10) + 0.5f) * 0.1f);
        float rely = posy - (-0.5f + ((px % 10) + 0.5f) * 0.1f);
        acc[mt][nt][r] = od + relx * wA + rely * wB;
      }
    }
  // ---- barrier-free K loop: act fully resident in LDS ----
  int gr0 = l16;                                  // row for mt=0
  int gr1 = (16 + l16 > 24) ? 24 : 16 + l16;      // clamped row for mt=1 (rows independent)
  const f16* wb0 = w1h + (size_t)(co0 + w * 32 + l16) * 1024 + quad * 8;
  const f16* wb1 = wb0 + (size_t)16 * 1024;
#pragma unroll 4
  for (int kq = 0; kq < 32; ++kq) {
    int k0 = kq * 32;
    half8 bf0 = *(const half8*)(wb0 + k0);
    half8 bf1 = *(const half8*)(wb1 + k0);
    half8 a0 = *(const half8*)(act + gr0 * 1032 + k0 + quad * 8);
    half8 a1 = *(const half8*)(act + gr1 * 1032 + k0 + quad * 8);
    acc[0][0] = MFMA16(a0, bf0, acc[0][0]);
    acc[1][0] = MFMA16(a1, bf0, acc[1][0]);
    acc[0][1] = MFMA16(a0, bf1, acc[0][1]);
    acc[1][1] = MFMA16(a1, bf1, acc[1][1]);
  }
#pragma unroll
  for (int mt = 0; mt < 2; ++mt)
#pragma unroll
    for (int nt = 0; nt < 2; ++nt) {
      int co = co0 + w * 32 + nt * 16 + l16;
#pragma unroll
      for (int r = 0; r < 4; ++r) {
        int pl = mt * 16 + quad * 4 + r;
        if (pl < 25)
          h1h[((size_t)n * 100 + p0 + pl) * 1024 + co] = (f16)fmaxf(acc[mt][nt][r], 0.0f);
      }
    }
}

// ======================= classifier layer 2 (1024 -> 256), MFMA =======================
__global__ __launch_bounds__(256) void cls2_mfma_k(
    const f16* __restrict__ h1h, const f16* __restrict__ w2h16,
    const float* __restrict__ b2, f16* __restrict__ h2h) {
  __shared__ f16 act[64 * 72];
  int b = blockIdx.x;
  int ng = b & 1, mh = (b >> 1) & 1, n = b >> 2;
  int co0 = ng * 128, p0 = mh * 50;
  int t = threadIdx.x, lane = t & 63, w = t >> 6;
  int quad = lane >> 4, l16 = lane & 15;
  f32x4 acc[4][2] = {};
  for (int kc = 0; kc < 16; ++kc) {
    int k0 = kc * 64;
    __syncthreads();
    for (int i = t; i < 512; i += 256) {
      int row = i >> 3, c8 = i & 7;                // rows 0..63
      int gr = p0 + (row < 50 ? row : 49);         // clamp; garbage rows never stored
      *(half8*)(act + row * 72 + c8 * 8) =
          *(const half8*)(h1h + ((size_t)n * 100 + gr) * 1024 + k0 + c8 * 8);
    }
    __syncthreads();
#pragma unroll
    for (int ks = 0; ks < 2; ++ks) {
      half8 bf0 = *(const half8*)(w2h16 + (size_t)(co0 + w * 32 + l16) * 1024 + k0 + ks * 32 + quad * 8);
      half8 bf1 = *(const half8*)(w2h16 + (size_t)(co0 + w * 32 + 16 + l16) * 1024 + k0 + ks * 32 + quad * 8);
#pragma unroll
      for (int mt = 0; mt < 4; ++mt) {
        half8 a = *(const half8*)(act + (mt * 16 + l16) * 72 + ks * 32 + quad * 8);
        acc[mt][0] = MFMA16(a, bf0, acc[mt][0]);
        acc[mt][1] = MFMA16(a, bf1, acc[mt][1]);
      }
    }
  }
#pragma unroll
  for (int mt = 0; mt < 4; ++mt)
#pragma unroll
    for (int nt = 0; nt < 2; ++nt) {
      int co = co0 + w * 32 + nt * 16 + l16;
      float bb = b2[co];
#pragma unroll
      for (int r = 0; r < 4; ++r) {
        int pl = mt * 16 + quad * 4 + r;
        if (pl < 50)
          h2h[((size_t)n * 100 + p0 + pl) * 256 + co] = (f16)fmaxf(acc[mt][nt][r] + bb, 0.0f);
      }
    }
}

// ======================= classifier layer 3 (256 -> 1) =======================
__global__ void cls3_k(const f16* __restrict__ h2h, const float* __restrict__ w3,
                       const float* __restrict__ b3, float* __restrict__ out) {
  int n = blockIdx.x, t = threadIdx.x;
  if (t < 100) {
    float acc = b3[0];
    const f16* hp = &h2h[((size_t)n * 100 + t) * 256];
    for (int k = 0; k < 256; ++k) acc = fmaf((float)hp[k], w3[k], acc);
    out[n * 100 + t] = acc;
  }
}

// ======================= launch =======================
extern "C" void kernel_launch(void* const* d_in, const int* in_sizes, int n_in,
                              void* d_out, int out_size, void* d_ws, size_t ws_size,
                              hipStream_t stream) {
  const float* sc      = (const float*)d_in[0];
  const float* oc      = (const float*)d_in[1];
  const float* pos     = (const float*)d_in[2];
  const float* mlp_w1  = (const float*)d_in[3];
  const float* mlp_b1  = (const float*)d_in[4];
  const float* mlp_w2  = (const float*)d_in[5];
  const float* mlp_b2  = (const float*)d_in[6];
  const float* conv1_w = (const float*)d_in[7];
  const float* conv1_b = (const float*)d_in[8];
  const float* conv2_w = (const float*)d_in[9];
  const float* conv2_b = (const float*)d_in[10];
  const float* convt_w = (const float*)d_in[11];
  const float* convt_b = (const float*)d_in[12];
  const float* sa_w1   = (const float*)d_in[13];
  const float* sa_b1   = (const float*)d_in[14];
  const float* sa_w2   = (const float*)d_in[15];
  const float* sa_b2   = (const float*)d_in[16];
  const float* sa_w3   = (const float*)d_in[17];
  const float* sa_b3   = (const float*)d_in[18];
  const float* sa_w4   = (const float*)d_in[19];
  const float* sa_b4   = (const float*)d_in[20];
  const float* cls_w1  = (const float*)d_in[21];
  const float* cls_b1  = (const float*)d_in[22];
  const float* cls_w2  = (const float*)d_in[23];
  const float* cls_b2  = (const float*)d_in[24];
  const float* cls_w3  = (const float*)d_in[25];
  const float* cls_b3  = (const float*)d_in[26];

  float* ws = (float*)d_ws;
  // ---- workspace layout (float units) ----
  f16*   w1h   = (f16*)ws;                         // 589,824 f (conv1 B-frag)
  f16*   w2h   = (f16*)(ws + 589824);              // 2,359,296 f (conv2 B-frag; reused: h1h)
  f16*   mw2h  = (f16*)(ws + 2949120);             // 16,384 f
  f16*   saw2h = (f16*)(ws + 2965504);             // 4,096 f
  f16*   saw3h = (f16*)(ws + 2969600);             // 16,384 f
  f16*   saw4h = (f16*)(ws + 2985984);             // 65,536 f
  f16*   cw1h  = (f16*)(ws + 3051520);             // 524,288 f
  f16*   ctwh  = (f16*)(ws + 3575808);             // 1,048,576 f (B-frag layout)
  f16*   cw2h  = (f16*)(ws + 4624384);             // 131,072 f ([256][1024] fp16)
  float* big   = ws + 4886528;                     // 3,276,800 f (voxg, g1buf, g2buf, odw)
  f16*   voxh  = (f16*)(ws + 8163328);             // 819,200 f (reused: f2h)
  f16*   f1h   = (f16*)(ws + 8982528);             // 819,200 f
  f16*   scnh  = (f16*)(ws + 9801728);             // 1,638,400 f (reused: h2h)
  float* obj   = ws + 11440128;                    // 16,384 f
  float* ocm   = ws + 11456512;                    // 64 f

  float* voxg  = big;                              // fp32 voxel merge buffer [32][400][256]
  f16*   g1buf = (f16*)big;                        // conv1 out (voxg dead after pack)
  f16*   g2buf = (f16*)big;                        // conv2 out (g1buf dead after pool1)
  f16*   f2h   = voxh;                             // pool2 out (voxh dead after conv1)
  f16*   h1h   = w2h;                              // cls1 out (w2h dead after conv2)
  f16*   h2h   = scnh;                             // cls2 out (scnh dead after cls1)
  float* odw   = big + 2097152;                    // 32,768 f (big dead after pool2)
  float* wab   = big + 2129920;                    // 2,048 f
  float* outp  = (float*)d_out;

  // ---- weight preps ----
  wfragprep_k<512, 256><<<512, 256, 0, stream>>>(conv1_w, w1h);
  wfragprep_k<1024, 512><<<1024, 256, 0, stream>>>(conv2_w, w2h);
  cvt16_k<<<32, 256, 0, stream>>>(mlp_w2, mw2h, 8192);
  cvt16_k<<<8, 256, 0, stream>>>(sa_w2, saw2h, 2048);
  cvt16_k<<<32, 256, 0, stream>>>(sa_w3, saw3h, 8192);
  cvt16_k<<<128, 256, 0, stream>>>(sa_w4, saw4h, 32768);
  cw1prep_k<<<4096, 256, 0, stream>>>(cls_w1, cw1h);
  ctprep_k<<<8192, 256, 0, stream>>>(convt_w, ctwh);
  cvt16_k<<<256, 256, 0, stream>>>(cls_w2, cw2h, 65536);

  hipMemsetAsync(obj, 0, (size_t)16384 * 4, stream);
  hipMemsetAsync(voxg, 0, (size_t)3276800 * 4, stream);
  ocmean_k<<<32, 256, 0, stream>>>(oc, ocm);

  pointnet_lds_k<<<1024, 256, 0, stream>>>(sc, mlp_w1, mlp_b1, mw2h, mlp_b2, voxg);
  cvt16_k<<<3200, 256, 0, stream>>>(voxg, voxh, 819200);

  convmfma_k<20, 20, 256, 512, 4><<<512, 256, 7 * 22 * 80, stream>>>(
      voxh, w1h, conv1_b, g1buf);
  pool1_k<<<3200, 256, 0, stream>>>(g1buf, f1h, scnh);
  convmfma_k<10, 10, 512, 1024, 2><<<512, 256, 7 * 12 * 80, stream>>>(
      f1h, w2h, conv2_b, g2buf);
  pool2_k<<<1600, 256, 0, stream>>>(g2buf, f2h);
  convt_mfma_k<<<512, 256, 0, stream>>>(f2h, ctwh, convt_b, scnh);

  sa_mfma_k<<<1024, 256, 0, stream>>>(oc, ocm, sa_w1, sa_b1, saw2h, sa_b2,
                                      saw3h, sa_b3, saw4h, sa_b4, obj);
  odprep_k<<<1024, 256, 0, stream>>>(obj, cls_w1, cls_b1, odw, wab);

  cls1_mfma_k<<<1024, 256, 0, stream>>>(scnh, odw, wab, pos, cw1h, h1h);
  cls2_mfma_k<<<128, 256, 0, stream>>>(h1h, cw2h, cls_b2, h2h);
  cls3_k<<<32, 128, 0, stream>>>(h2h, cls_w3, cls_b3, outp);
}

// Round 7
// 475.547 us; speedup vs baseline: 1.1047x; 1.0467x over previous
//
#include <hip/hip_runtime.h>

#define NB 32
#define PP 8192
#define OPP 2048

typedef _Float16 f16;
typedef f16 half8 __attribute__((ext_vector_type(8)));
typedef f16 half4 __attribute__((ext_vector_type(4)));
typedef f16 half2v __attribute__((ext_vector_type(2)));
typedef float f32x4 __attribute__((ext_vector_type(4)));

#define MFMA16(a, b, c) __builtin_amdgcn_mfma_f32_16x16x32_f16(a, b, c, 0, 0, 0)

// ======================= fused prep: all weight conversions + ocmean in ONE dispatch ===========
// blocks [0,2048): elementwise/gather segments (grid-stride)
// blocks [2048,2080): ocmean (n = b-2048)
// blocks [2080,2592): conv1 wfrag (co = b-2080, CI=256, NBB=32)
// blocks [2592,3616): conv2 wfrag (co = b-2592, CI=512, NBB=64)
__global__ __launch_bounds__(256) void prepfuse_k(
    const float* __restrict__ mlp_w2, const float* __restrict__ sa_w2,
    const float* __restrict__ sa_w3, const float* __restrict__ sa_w4,
    const float* __restrict__ cls_w2, const float* __restrict__ cls_w1,
    const float* __restrict__ convt_w, const float* __restrict__ conv1_w,
    const float* __restrict__ conv2_w, const float* __restrict__ oc,
    f16* __restrict__ mw2h, f16* __restrict__ saw2h, f16* __restrict__ saw3h,
    f16* __restrict__ saw4h, f16* __restrict__ cw2h, f16* __restrict__ cw1h,
    f16* __restrict__ ctwh, f16* __restrict__ w1h, f16* __restrict__ w2h,
    float* __restrict__ ocm) {
  __shared__ float tile[512 * 9];          // 18,432 B (wfrag staging; reused by ocmean)
  int bb = blockIdx.x, t = threadIdx.x;
  if (bb < 2048) {
    constexpr int B0 = 8192, B1 = B0 + 2048, B2 = B1 + 8192, B3 = B2 + 32768, B4 = B3 + 65536;
    constexpr int C1e = B4 + 524288;       // cw1 float2 items
    constexpr int TOT = C1e + 2097152;     // ct scalar items
    for (int idx = bb * 256 + t; idx < TOT; idx += 2048 * 256) {
      if (idx < B4) {                      // five float4 -> half4 conversions
        const float* in; f16* out; int off;
        if (idx < B0)      { in = mlp_w2; out = mw2h;  off = idx; }
        else if (idx < B1) { in = sa_w2;  out = saw2h; off = idx - B0; }
        else if (idx < B2) { in = sa_w3;  out = saw3h; off = idx - B1; }
        else if (idx < B3) { in = sa_w4;  out = saw4h; off = idx - B2; }
        else               { in = cls_w2; out = cw2h;  off = idx - B3; }
        float4 v = ((const float4*)in)[off];
        half4 h; h.x = (f16)v.x; h.y = (f16)v.y; h.z = (f16)v.z; h.w = (f16)v.w;
        ((half4*)out)[off] = h;
      } else if (idx < C1e) {              // cls_w1 scene part [1024][1538] -> [1024][1024] fp16
        int i = idx - B4;
        int co = i >> 9, k2 = i & 511;
        float2 v = *(const float2*)(cls_w1 + (size_t)co * 1538 + k2 * 2);
        half2v h = {(f16)v.x, (f16)v.y};
        *(half2v*)(cw1h + (size_t)co * 1024 + k2 * 2) = h;
      } else {                             // convt_w -> MFMA B-fragment layout
        int i = idx - C1e;
        int j = i & 7, l = (i >> 3) & 63, kb = (i >> 9) & 31, nb = i >> 14;
        int n16 = l & 15, quad = l >> 4;
        int np = nb * 16 + n16;
        int k = kb * 32 + quad * 8 + j;
        int p = np >> 9, o = np & 511;
        ctwh[i] = (f16)convt_w[((size_t)o * 1024 + k) * 4 + (3 - p)];
      }
    }
  } else if (bb < 2080) {                  // ocmean
    float* sx = tile; float* sy = tile + 256;
    int n = bb - 2048;
    float ax = 0.f, ay = 0.f;
    for (int p = t; p < OPP; p += 256) {
      ax += oc[((size_t)n * OPP + p) * 2 + 0];
      ay += oc[((size_t)n * OPP + p) * 2 + 1];
    }
    sx[t] = ax; sy[t] = ay;
    __syncthreads();
    for (int s = 128; s > 0; s >>= 1) {
      if (t < s) { sx[t] += sx[t + s]; sy[t] += sy[t + s]; }
      __syncthreads();
    }
    if (t == 0) {
      ocm[n * 2 + 0] = sx[0] / (float)OPP;
      ocm[n * 2 + 1] = sy[0] / (float)OPP;
    }
  } else {                                 // conv wfrag (runtime-parameterized)
    int co, CI, NBB; const float* src0; f16* wf;
    if (bb < 2592) { co = bb - 2080; CI = 256; NBB = 32; src0 = conv1_w; wf = w1h; }
    else           { co = bb - 2592; CI = 512; NBB = 64; src0 = conv2_w; wf = w2h; }
    const float* src = src0 + (size_t)co * CI * 9;
    for (int i = t; i < CI * 9; i += 256) tile[i] = src[i];
    __syncthreads();
    int nb = co >> 4, l16c = co & 15;
    int tot = (CI / 32) * 9 * 4;
    for (int e = t; e < tot; e += 256) {
      int quad = e & 3;
      int kk = (e >> 2) % 9;
      int cic = e / 36;
      half8 v;
#pragma unroll
      for (int j = 0; j < 8; ++j) v[j] = (f16)tile[(cic * 32 + quad * 8 + j) * 9 + kk];
      *(half8*)(wf + ((((size_t)cic * 9 + kk) * NBB + nb) * 64 + quad * 16 + l16c) * 8) = v;
    }
  }
}

__global__ void cvt16_k(const float* __restrict__ in, f16* __restrict__ out, int n4) {
  int idx = blockIdx.x * 256 + threadIdx.x;
  if (idx >= n4) return;
  float4 v = ((const float4*)in)[idx];
  half4 h; h.x = (f16)v.x; h.y = (f16)v.y; h.z = (f16)v.z; h.w = (f16)v.w;
  ((half4*)out)[idx] = h;
}

// ======================= voxel PointNet: barrier-free LDS scatter-max =======================
// 512-thread blocks: grid = 32n * 8cg * 2ps = 512 blocks -> 2 blocks/CU = 16 waves/CU
// (VGPR-capped; was 12 waves with 256-thread blocks). Layer-1 in packed fp16.
__global__ __launch_bounds__(512) void pointnet_lds_k(
    const float* __restrict__ sc, const float* __restrict__ w1, const float* __restrict__ b1,
    const f16* __restrict__ w2h, const float* __restrict__ b2, float* __restrict__ voxg) {
  __shared__ float voxl[400 * 33];         // 52,800 B
  int t = threadIdx.x, lane = t & 63, w = t >> 6;   // w 0..7
  int quad = lane >> 4, l16 = lane & 15;
  int b = blockIdx.x;
  int ps = b & 1, cg = (b >> 1) & 7, n = b >> 4;
  // packed layer-1 weights: this quad's 32 channels => 16 half2 per array
  half2v w1x2[16], w1y2[16], b12[16];
#pragma unroll
  for (int i = 0; i < 16; ++i) {
    int k0 = (i >> 2) * 32 + quad * 8 + (i & 3) * 2;   // ks = i>>2, j2 = i&3
    w1x2[i] = (half2v){(f16)w1[k0 * 2], (f16)w1[(k0 + 1) * 2]};
    w1y2[i] = (half2v){(f16)w1[k0 * 2 + 1], (f16)w1[(k0 + 1) * 2 + 1]};
    b12[i]  = (half2v){(f16)b1[k0], (f16)b1[k0 + 1]};
  }
  half8 bf[2][4];
  float bias[2];
#pragma unroll
  for (int nt = 0; nt < 2; ++nt) {
    int ch = cg * 32 + nt * 16 + l16;
    bias[nt] = b2[ch];
#pragma unroll
    for (int ks = 0; ks < 4; ++ks)
      bf[nt][ks] = *(const half8*)(w2h + (size_t)ch * 128 + ks * 32 + quad * 8);
  }
  for (int i = t; i < 400 * 33; i += 512) voxl[i] = 0.0f;
  __syncthreads();
  const half2v z2 = {};
  const float* scp = sc + ((size_t)n * PP + (size_t)ps * 4096) * 2;
  int p0 = w * 16 + l16;
  float2 xy = *(const float2*)(scp + p0 * 2);
  for (int it = 0; it < 32; ++it) {
    float x = xy.x, y = xy.y;
    if (it < 31) xy = *(const float2*)(scp + ((it + 1) * 128 + p0) * 2);
    float bif = fminf(fmaxf(ceilf((x + 0.5f) * 20.0f) - 1.0f, 0.0f), 19.0f);
    float bjf = fminf(fmaxf(ceilf((y + 0.5f) * 20.0f) - 1.0f, 0.0f), 19.0f);
    bool valid = (x > -0.5f) && (x <= 0.5f) && (y > -0.5f) && (y <= 0.5f);
    float px = x - (-0.5f + (bif + 0.5f) * 0.05f);
    float py = y - (-0.5f + (bjf + 0.5f) * 0.05f);
    int bn = valid ? ((int)bif * 20 + (int)bjf) : -1;
    f16 pxh = (f16)px, pyh = (f16)py;
    half2v px2 = (half2v){pxh, pxh}, py2 = (half2v){pyh, pyh};
    f32x4 acc0 = {}, acc1 = {};
#pragma unroll
    for (int ks = 0; ks < 4; ++ks) {
      half8 af;
#pragma unroll
      for (int j2 = 0; j2 < 4; ++j2) {
        half2v tmp = w1x2[ks * 4 + j2] * px2 + (w1y2[ks * 4 + j2] * py2 + b12[ks * 4 + j2]);
        tmp = __builtin_elementwise_max(tmp, z2);
        reinterpret_cast<half2v*>(&af)[j2] = tmp;
      }
      acc0 = MFMA16(af, bf[0][ks], acc0);
      acc1 = MFMA16(af, bf[1][ks], acc1);
    }
#pragma unroll
    for (int r = 0; r < 4; ++r) {
      int bn2 = __shfl(bn, quad * 4 + r);
      if (bn2 >= 0) {
        float v0 = fmaxf(acc0[r] + bias[0], 0.0f);
        float v1 = fmaxf(acc1[r] + bias[1], 0.0f);
        atomicMax((int*)voxl + bn2 * 33 + l16, __float_as_int(v0));
        atomicMax((int*)voxl + bn2 * 33 + 16 + l16, __float_as_int(v1));
      }
    }
  }
  __syncthreads();
  // merge private LDS grid into the global fp32 voxel buffer
  float* vg = voxg + ((size_t)n * 400) * 256 + cg * 32;
  for (int i = t; i < 400 * 32; i += 512) {
    int bin = i >> 5, c = i & 31;
    float v = voxl[bin * 33 + c];
    if (v > 0.0f)
      atomicMax((int*)(vg + (size_t)bin * 256) + c, __float_as_int(v));
  }
}

// ======================= MFMA implicit-GEMM conv 3x3 pad1 + relu =======================
template <int H, int W, int CI, int CO, int MSPLIT>
__global__ __launch_bounds__(256, 2) void convmfma_k(
    const f16* __restrict__ inh, const f16* __restrict__ wf,
    const float* __restrict__ bias, f16* __restrict__ outh) {
  constexpr int HS = H / MSPLIT;
  constexpr int Mpix = HS * W;
  constexpr int MT = (Mpix + 15) / 16;
  constexpr int PR = HS + 2, PC = W + 2;
  constexpr int NCIC = CI / 32;
  constexpr int COG = CO / 128;
  constexpr int NBB = CO / 16;
  extern __shared__ char smem[];
  f16* Ap = (f16*)smem;                          // [PR*PC][40]
  int b = blockIdx.x;
  int cog = b % COG;
  int ms = (b / COG) % MSPLIT;
  int n = b / (COG * MSPLIT);
  int co0 = cog * 128;
  int r0 = ms * HS;
  int t = threadIdx.x, lane = t & 63, w = t >> 6;
  int quad = lane >> 4, l16 = lane & 15;
  int nb0 = cog * 8 + w * 2;                     // B-fragment row-block (16 co each)

  int abase[MT];
#pragma unroll
  for (int mi = 0; mi < MT; ++mi) {
    int pl = mi * 16 + l16; if (pl > Mpix - 1) pl = Mpix - 1;
    int y = pl / W, x = pl - y * W;
    abase[mi] = (y * PC + x) * 40 + quad * 8;    // halves
  }
  f32x4 acc[MT][2] = {};

  const f16* inbase = inh + (size_t)n * H * W * CI;

  for (int cic = 0; cic < NCIC; ++cic) {
    __syncthreads();                             // protect Ap from prior reads
    for (int cell = t; cell < PR * PC; cell += 256) {
      int pr = cell / PC, pc = cell - pr * PC;
      int yin = r0 - 1 + pr, xin = pc - 1;
      uint4 d0 = {0,0,0,0}, d1 = {0,0,0,0}, d2 = {0,0,0,0}, d3 = {0,0,0,0};
      if (yin >= 0 && yin < H && xin >= 0 && xin < W) {
        const uint4* src = (const uint4*)(inbase + ((size_t)yin * W + xin) * CI + cic * 32);
        d0 = src[0]; d1 = src[1]; d2 = src[2]; d3 = src[3];
      }
      uint4* dst = (uint4*)(Ap + cell * 40);
      dst[0] = d0; dst[1] = d1; dst[2] = d2; dst[3] = d3;
    }
    __syncthreads();
    const f16* wfc = wf + (size_t)(cic * 9) * NBB * 512;
#pragma unroll
    for (int ky = 0; ky < 3; ++ky)
#pragma unroll
      for (int kx = 0; kx < 3; ++kx) {
        int kk = ky * 3 + kx;
        half8 bf0 = *(const half8*)(wfc + ((size_t)(kk * NBB + nb0) * 64 + lane) * 8);
        half8 bf1 = *(const half8*)(wfc + ((size_t)(kk * NBB + nb0 + 1) * 64 + lane) * 8);
        int shift = (ky * PC + kx) * 40;
#pragma unroll
        for (int mi = 0; mi < MT; ++mi) {
          half8 af = *(const half8*)(Ap + abase[mi] + shift);
          acc[mi][0] = MFMA16(af, bf0, acc[mi][0]);
          acc[mi][1] = MFMA16(af, bf1, acc[mi][1]);
        }
      }
  }
  int co_w = co0 + w * 32;
  float bv0 = bias[co_w + l16];
  float bv1 = bias[co_w + 16 + l16];
  f16* ob = outh + ((size_t)n * H * W + (size_t)ms * Mpix) * CO;
#pragma unroll
  for (int mi = 0; mi < MT; ++mi) {
#pragma unroll
    for (int r = 0; r < 4; ++r) {
      int p = mi * 16 + quad * 4 + r;
      if (p < Mpix) {
        float v0 = acc[mi][0][r] + bv0; v0 = v0 > 0.f ? v0 : 0.f;
        float v1 = acc[mi][1][r] + bv1; v1 = v1 > 0.f ? v1 : 0.f;
        ob[(size_t)p * CO + co_w + l16] = (f16)v0;
        ob[(size_t)p * CO + co_w + 16 + l16] = (f16)v1;
      }
    }
  }
}

// ======================= maxpool 2x2 (+ fused pack into scene buffer) =======================
__global__ void pool1_k(const f16* __restrict__ g1, f16* __restrict__ f1h,
                        f16* __restrict__ scnh) {
  int idx = blockIdx.x * 256 + threadIdx.x;
  if (idx >= 32 * 100 * 256) return;
  int c2 = idx & 255, rem = idx >> 8;
  int op = rem % 100, n = rem / 100;
  int py = op / 10, px = op - py * 10;
  const f16* base = g1 + (((size_t)n * 400 + (size_t)(2 * py) * 20 + 2 * px) * 512) + c2 * 2;
  float a0 = (float)base[0],   a1 = (float)base[1];
  float b0 = (float)base[512], b1 = (float)base[513];
  const f16* base2 = base + 20 * 512;
  float c0 = (float)base2[0],   c1 = (float)base2[1];
  float d0 = (float)base2[512], d1 = (float)base2[513];
  union { f16 h[2]; unsigned u; } pk;
  pk.h[0] = (f16)fmaxf(fmaxf(a0, b0), fmaxf(c0, d0));
  pk.h[1] = (f16)fmaxf(fmaxf(a1, b1), fmaxf(c1, d1));
  *(unsigned*)(f1h + ((size_t)n * 100 + op) * 512 + c2 * 2) = pk.u;
  *(unsigned*)(scnh + ((size_t)n * 100 + op) * 1024 + c2 * 2) = pk.u;
}

__global__ void pool2_k(const f16* __restrict__ g2, f16* __restrict__ f2h) {
  int idx = blockIdx.x * 256 + threadIdx.x;
  if (idx >= 32 * 25 * 512) return;
  int c2 = idx & 511, rem = idx >> 9;
  int op = rem % 25, n = rem / 25;
  int py = op / 5, px = op - py * 5;
  const f16* base = g2 + (((size_t)n * 100 + (size_t)(2 * py) * 10 + 2 * px) * 1024) + c2 * 2;
  float a0 = (float)base[0],    a1 = (float)base[1];
  float b0 = (float)base[1024], b1 = (float)base[1025];
  const f16* base2 = base + 10 * 1024;
  float c0 = (float)base2[0],    c1 = (float)base2[1];
  float d0 = (float)base2[1024], d1 = (float)base2[1025];
  f16* o = f2h + ((size_t)n * 25 + op) * 1024 + c2 * 2;
  o[0] = (f16)fmaxf(fmaxf(a0, b0), fmaxf(c0, d0));
  o[1] = (f16)fmaxf(fmaxf(a1, b1), fmaxf(c1, d1));
}

// ======================= conv transpose 2x2 s2 (1024->512), MFMA v2 =======================
__global__ __launch_bounds__(256, 2) void convt_mfma_k(
    const f16* __restrict__ f2h, const f16* __restrict__ ctwf,
    const float* __restrict__ ctb, f16* __restrict__ scnh) {
  __shared__ f16 act[25 * 1048];           // 52,400 B
  int b = blockIdx.x;
  int ng = b & 15, n = b >> 4;
  int t = threadIdx.x, lane = t & 63, w = t >> 6;
  int quad = lane >> 4, l16 = lane & 15;
  for (int i = t; i < 25 * 128; i += 256) {
    int row = i >> 7, c8 = i & 127;
    *(half8*)(act + row * 1048 + c8 * 8) =
        *(const half8*)(f2h + ((size_t)n * 25 + row) * 1024 + c8 * 8);
  }
  __syncthreads();
  int r1 = 16 + (l16 > 8 ? 8 : l16);       // clamp: garbage rows never stored
  f32x4 acc[2][2] = {};
  const f16* wp0 = ctwf + ((size_t)((ng * 8 + w * 2 + 0) * 32) * 64 + lane) * 8;
  const f16* wp1 = ctwf + ((size_t)((ng * 8 + w * 2 + 1) * 32) * 64 + lane) * 8;
#pragma unroll 4
  for (int ks = 0; ks < 32; ++ks) {
    half8 a0 = *(const half8*)(act + l16 * 1048 + ks * 32 + quad * 8);
    half8 a1 = *(const half8*)(act + r1 * 1048 + ks * 32 + quad * 8);
    half8 b0 = *(const half8*)(wp0 + (size_t)ks * 512);
    half8 b1 = *(const half8*)(wp1 + (size_t)ks * 512);
    acc[0][0] = MFMA16(a0, b0, acc[0][0]);
    acc[1][0] = MFMA16(a1, b0, acc[1][0]);
    acc[0][1] = MFMA16(a0, b1, acc[0][1]);
    acc[1][1] = MFMA16(a1, b1, acc[1][1]);
  }
#pragma unroll
  for (int nt = 0; nt < 2; ++nt) {
    int np = ng * 128 + w * 32 + nt * 16 + l16;
    int p = np >> 9, co = np & 511;
    int a = p >> 1, bc = p & 1;
    float bb = ctb[co];
#pragma unroll
    for (int mt = 0; mt < 2; ++mt)
#pragma unroll
      for (int r = 0; r < 4; ++r) {
        int px = mt * 16 + quad * 4 + r;
        if (px < 25) {
          int ph = px / 5, pw = px - ph * 5;
          int opx = (2 * ph + a) * 10 + 2 * pw + bc;
          scnh[((size_t)n * 100 + opx) * 1024 + 512 + co] = (f16)(acc[mt][nt][r] + bb);
        }
      }
  }
}

// ======================= object SA: fused 4-layer MFMA + max (M=64 tiles) =======================
__global__ __launch_bounds__(256, 2) void sa_mfma_k(
    const float* __restrict__ oc, const float* __restrict__ ocm,
    const float* __restrict__ w1, const float* __restrict__ b1,
    const f16* __restrict__ w2h, const float* __restrict__ b2,
    const f16* __restrict__ w3h, const float* __restrict__ b3,
    const f16* __restrict__ w4h, const float* __restrict__ b4,
    float* __restrict__ obj) {
  __shared__ f16 act1[64 * 72];            // 9,216 B [pt][K=64]
  __shared__ f16 act2[64 * 136];           // 17,408 B [pt][K=128]
  __shared__ f16 act3[64 * 264];           // 33,792 B [pt][K=256]
  __shared__ float pcx[64], pcy[64];
  int b = blockIdx.x;                      // 1024 = 32 n * 32 chunks of 64 pts
  int n = b >> 5, pb = (b & 31) * 64;
  int t = threadIdx.x, lane = t & 63, w = t >> 6;
  int quad = lane >> 4, l16 = lane & 15;
  if (t < 64) {
    pcx[t] = oc[((size_t)n * OPP + pb + t) * 2 + 0] - ocm[n * 2 + 0];
    pcy[t] = oc[((size_t)n * OPP + pb + t) * 2 + 1] - ocm[n * 2 + 1];
  }
  __syncthreads();
  {                                        // layer1: 2 -> 64 for 64 points
    int c = t & 63, pg = t >> 6;
    float wx = w1[c * 2], wy = w1[c * 2 + 1], bb = b1[c];
#pragma unroll
    for (int j = 0; j < 16; ++j) {
      int p = pg * 16 + j;
      act1[p * 72 + c] = (f16)fmaxf(fmaf(wx, pcx[p], fmaf(wy, pcy[p], bb)), 0.0f);
    }
  }
  __syncthreads();
  {                                        // layer2: M=64, K=64, N=128; wave n-range 32
    int n0 = w * 32;
    f32x4 acc[4][2] = {};
#pragma unroll
    for (int ks = 0; ks < 2; ++ks) {
      half8 a[4];
#pragma unroll
      for (int mt = 0; mt < 4; ++mt)
        a[mt] = *(const half8*)(act1 + (mt * 16 + l16) * 72 + ks * 32 + quad * 8);
#pragma unroll
      for (int nt = 0; nt < 2; ++nt) {
        half8 bf = *(const half8*)(w2h + (size_t)(n0 + nt * 16 + l16) * 64 + ks * 32 + quad * 8);
#pragma unroll
        for (int mt = 0; mt < 4; ++mt)
          acc[mt][nt] = MFMA16(a[mt], bf, acc[mt][nt]);
      }
    }
#pragma unroll
    for (int nt = 0; nt < 2; ++nt) {
      int col = n0 + nt * 16 + l16;
      float bb = b2[col];
#pragma unroll
      for (int mt = 0; mt < 4; ++mt)
#pragma unroll
        for (int r = 0; r < 4; ++r)
          act2[(mt * 16 + quad * 4 + r) * 136 + col] = (f16)fmaxf(acc[mt][nt][r] + bb, 0.0f);
    }
  }
  __syncthreads();
  {                                        // layer3: M=64, K=128, N=256; wave n-range 64
    int n0 = w * 64;
    f32x4 acc[4][4] = {};
#pragma unroll
    for (int ks = 0; ks < 4; ++ks) {
      half8 a[4];
#pragma unroll
      for (int mt = 0; mt < 4; ++mt)
        a[mt] = *(const half8*)(act2 + (mt * 16 + l16) * 136 + ks * 32 + quad * 8);
#pragma unroll
      for (int nt = 0; nt < 4; ++nt) {
        half8 bf = *(const half8*)(w3h + (size_t)(n0 + nt * 16 + l16) * 128 + ks * 32 + quad * 8);
#pragma unroll
        for (int mt = 0; mt < 4; ++mt)
          acc[mt][nt] = MFMA16(a[mt], bf, acc[mt][nt]);
      }
    }
#pragma unroll
    for (int nt = 0; nt < 4; ++nt) {
      int col = n0 + nt * 16 + l16;
      float bb = b3[col];
#pragma unroll
      for (int mt = 0; mt < 4; ++mt)
#pragma unroll
        for (int r = 0; r < 4; ++r)
          act3[(mt * 16 + quad * 4 + r) * 264 + col] = (f16)fmaxf(acc[mt][nt][r] + bb, 0.0f);
    }
  }
  __syncthreads();
  {                                        // layer4: M=64, K=256, N=512; wave n-range 128; + max
    int n0 = w * 128;
    f32x4 acc[4][8] = {};
#pragma unroll
    for (int ks = 0; ks < 8; ++ks) {
      half8 a[4];
#pragma unroll
      for (int mt = 0; mt < 4; ++mt)
        a[mt] = *(const half8*)(act3 + (mt * 16 + l16) * 264 + ks * 32 + quad * 8);
#pragma unroll
      for (int nt = 0; nt < 8; ++nt) {
        half8 bf = *(const half8*)(w4h + (size_t)(n0 + nt * 16 + l16) * 256 + ks * 32 + quad * 8);
#pragma unroll
        for (int mt = 0; mt < 4; ++mt)
          acc[mt][nt] = MFMA16(a[mt], bf, acc[mt][nt]);
      }
    }
#pragma unroll
    for (int nt = 0; nt < 8; ++nt) {
      int col = n0 + nt * 16 + l16;
      float bb = b4[col];
      float v = 0.0f;
#pragma unroll
      for (int mt = 0; mt < 4; ++mt)
#pragma unroll
        for (int r = 0; r < 4; ++r)
          v = fmaxf(v, acc[mt][nt][r] + bb);
      v = fmaxf(v, 0.0f);
      v = fmaxf(v, __shfl_xor(v, 16));
      v = fmaxf(v, __shfl_xor(v, 32));
      if (quad == 0)
        atomicMax((int*)obj + (size_t)n * 512 + col, __float_as_int(v));
    }
  }
}

// ======================= obj-dot precompute: odw[n][co] = obj[n]·w1raw[co,1024:1536] + b1 =======
__global__ __launch_bounds__(256) void odprep_k(
    const float* __restrict__ obj, const float* __restrict__ w1raw,
    const float* __restrict__ b1, float* __restrict__ odw, float* __restrict__ wab) {
  int co = blockIdx.x;
  int t = threadIdx.x, lane = t & 63, w = t >> 6;
  const float* wr = w1raw + (size_t)co * 1538 + 1024;
  float2 wv[4];
#pragma unroll
  for (int j = 0; j < 4; ++j) wv[j] = *(const float2*)(wr + lane * 8 + j * 2);
  float bb = b1[co];
  for (int i = 0; i < 8; ++i) {
    int n = w * 8 + i;
    const float* ob = obj + (size_t)n * 512 + lane * 8;
    float od = 0.0f;
#pragma unroll
    for (int j = 0; j < 4; ++j) {
      float2 ov = *(const float2*)(ob + j * 2);
      od = fmaf(wv[j].x, ov.x, od);
      od = fmaf(wv[j].y, ov.y, od);
    }
    od += __shfl_xor(od, 1);  od += __shfl_xor(od, 2);
    od += __shfl_xor(od, 4);  od += __shfl_xor(od, 8);
    od += __shfl_xor(od, 16); od += __shfl_xor(od, 32);
    if (lane == 0) odw[(size_t)n * 1024 + co] = od + bb;
  }
  if (t == 0) { wab[co * 2] = wr[512]; wab[co * 2 + 1] = wr[513]; }
}

// ======================= classifier layer 1 (1538 -> 1024), MFMA =======================
// grid = 1024; o8 = b&7 so all blocks sharing a w1h octant slice land on ONE XCD.
__global__ __launch_bounds__(256) void cls1_mfma_k(
    const f16* __restrict__ scnh, const float* __restrict__ odw,
    const float* __restrict__ wab, const float* __restrict__ pos,
    const f16* __restrict__ w1h, f16* __restrict__ h1h) {
  __shared__ f16 act[25 * 1032];           // 51,600 B
  __shared__ float odl[128], wAl[128], wBl[128];
  int b = blockIdx.x;
  int o8 = b & 7, mq = (b >> 3) & 3, n = b >> 5;
  int co0 = o8 * 128, p0 = mq * 25;
  int t = threadIdx.x, lane = t & 63, w = t >> 6;
  int quad = lane >> 4, l16 = lane & 15;
  for (int i = t; i < 25 * 128; i += 256) {
    int row = i >> 7, c8 = i & 127;
    *(half8*)(act + row * 1032 + c8 * 8) =
        *(const half8*)(scnh + ((size_t)n * 100 + p0 + row) * 1024 + c8 * 8);
  }
  if (t < 128) {
    odl[t] = odw[(size_t)n * 1024 + co0 + t];
    float2 ab = *(const float2*)(wab + (size_t)(co0 + t) * 2);
    wAl[t] = ab.x; wBl[t] = ab.y;
  }
  __syncthreads();
  float posx = pos[n * 2 + 0], posy = pos[n * 2 + 1];
  f32x4 acc[2][2];
#pragma unroll
  for (int mt = 0; mt < 2; ++mt)
#pragma unroll
    for (int nt = 0; nt < 2; ++nt) {
      int cl = w * 32 + nt * 16 + l16;
      float od = odl[cl], wA = wAl[cl], wB = wBl[cl];
#pragma unroll
      for (int r = 0; r < 4; ++r) {
        int pl = mt * 16 + quad * 4 + r;
        int px = p0 + (pl < 25 ? pl : 24);         // clamped lanes never stored
        float relx = posx - (-0.5f + ((px / 10) + 0.5f) * 0.1f);
        float rely = posy - (-0.5f + ((px % 10) + 0.5f) * 0.1f);
        acc[mt][nt][r] = od + relx * wA + rely * wB;
      }
    }
  int gr0 = l16;
  int gr1 = (16 + l16 > 24) ? 24 : 16 + l16;
  const f16* wb0 = w1h + (size_t)(co0 + w * 32 + l16) * 1024 + quad * 8;
  const f16* wb1 = wb0 + (size_t)16 * 1024;
#pragma unroll 4
  for (int kq = 0; kq < 32; ++kq) {
    int k0 = kq * 32;
    half8 bf0 = *(const half8*)(wb0 + k0);
    half8 bf1 = *(const half8*)(wb1 + k0);
    half8 a0 = *(const half8*)(act + gr0 * 1032 + k0 + quad * 8);
    half8 a1 = *(const half8*)(act + gr1 * 1032 + k0 + quad * 8);
    acc[0][0] = MFMA16(a0, bf0, acc[0][0]);
    acc[1][0] = MFMA16(a1, bf0, acc[1][0]);
    acc[0][1] = MFMA16(a0, bf1, acc[0][1]);
    acc[1][1] = MFMA16(a1, bf1, acc[1][1]);
  }
#pragma unroll
  for (int mt = 0; mt < 2; ++mt)
#pragma unroll
    for (int nt = 0; nt < 2; ++nt) {
      int co = co0 + w * 32 + nt * 16 + l16;
#pragma unroll
      for (int r = 0; r < 4; ++r) {
        int pl = mt * 16 + quad * 4 + r;
        if (pl < 25)
          h1h[((size_t)n * 100 + p0 + pl) * 1024 + co] = (f16)fmaxf(acc[mt][nt][r], 0.0f);
      }
    }
}

// ======================= classifier layer 2 (1024 -> 256), MFMA =======================
__global__ __launch_bounds__(256) void cls2_mfma_k(
    const f16* __restrict__ h1h, const f16* __restrict__ w2h16,
    const float* __restrict__ b2, f16* __restrict__ h2h) {
  __shared__ f16 act[64 * 72];
  int b = blockIdx.x;
  int ng = b & 1, mh = (b >> 1) & 1, n = b >> 2;
  int co0 = ng * 128, p0 = mh * 50;
  int t = threadIdx.x, lane = t & 63, w = t >> 6;
  int quad = lane >> 4, l16 = lane & 15;
  f32x4 acc[4][2] = {};
  for (int kc = 0; kc < 16; ++kc) {
    int k0 = kc * 64;
    __syncthreads();
    for (int i = t; i < 512; i += 256) {
      int row = i >> 3, c8 = i & 7;                // rows 0..63
      int gr = p0 + (row < 50 ? row : 49);         // clamp; garbage rows never stored
      *(half8*)(act + row * 72 + c8 * 8) =
          *(const half8*)(h1h + ((size_t)n * 100 + gr) * 1024 + k0 + c8 * 8);
    }
    __syncthreads();
#pragma unroll
    for (int ks = 0; ks < 2; ++ks) {
      half8 bf0 = *(const half8*)(w2h16 + (size_t)(co0 + w * 32 + l16) * 1024 + k0 + ks * 32 + quad * 8);
      half8 bf1 = *(const half8*)(w2h16 + (size_t)(co0 + w * 32 + 16 + l16) * 1024 + k0 + ks * 32 + quad * 8);
#pragma unroll
      for (int mt = 0; mt < 4; ++mt) {
        half8 a = *(const half8*)(act + (mt * 16 + l16) * 72 + ks * 32 + quad * 8);
        acc[mt][0] = MFMA16(a, bf0, acc[mt][0]);
        acc[mt][1] = MFMA16(a, bf1, acc[mt][1]);
      }
    }
  }
#pragma unroll
  for (int mt = 0; mt < 4; ++mt)
#pragma unroll
    for (int nt = 0; nt < 2; ++nt) {
      int co = co0 + w * 32 + nt * 16 + l16;
      float bb = b2[co];
#pragma unroll
      for (int r = 0; r < 4; ++r) {
        int pl = mt * 16 + quad * 4 + r;
        if (pl < 50)
          h2h[((size_t)n * 100 + p0 + pl) * 256 + co] = (f16)fmaxf(acc[mt][nt][r] + bb, 0.0f);
      }
    }
}

// ======================= classifier layer 3 (256 -> 1) =======================
__global__ void cls3_k(const f16* __restrict__ h2h, const float* __restrict__ w3,
                       const float* __restrict__ b3, float* __restrict__ out) {
  int n = blockIdx.x, t = threadIdx.x;
  if (t < 100) {
    float acc = b3[0];
    const f16* hp = &h2h[((size_t)n * 100 + t) * 256];
    for (int k = 0; k < 256; ++k) acc = fmaf((float)hp[k], w3[k], acc);
    out[n * 100 + t] = acc;
  }
}

// ======================= launch =======================
extern "C" void kernel_launch(void* const* d_in, const int* in_sizes, int n_in,
                              void* d_out, int out_size, void* d_ws, size_t ws_size,
                              hipStream_t stream) {
  const float* sc      = (const float*)d_in[0];
  const float* oc      = (const float*)d_in[1];
  const float* pos     = (const float*)d_in[2];
  const float* mlp_w1  = (const float*)d_in[3];
  const float* mlp_b1  = (const float*)d_in[4];
  const float* mlp_w2  = (const float*)d_in[5];
  const float* mlp_b2  = (const float*)d_in[6];
  const float* conv1_w = (const float*)d_in[7];
  const float* conv1_b = (const float*)d_in[8];
  const float* conv2_w = (const float*)d_in[9];
  const float* conv2_b = (const float*)d_in[10];
  const float* convt_w = (const float*)d_in[11];
  const float* convt_b = (const float*)d_in[12];
  const float* sa_w1   = (const float*)d_in[13];
  const float* sa_b1   = (const float*)d_in[14];
  const float* sa_w2   = (const float*)d_in[15];
  const float* sa_b2   = (const float*)d_in[16];
  const float* sa_w3   = (const float*)d_in[17];
  const float* sa_b3   = (const float*)d_in[18];
  const float* sa_w4   = (const float*)d_in[19];
  const float* sa_b4   = (const float*)d_in[20];
  const float* cls_w1  = (const float*)d_in[21];
  const float* cls_b1  = (const float*)d_in[22];
  const float* cls_w2  = (const float*)d_in[23];
  const float* cls_b2  = (const float*)d_in[24];
  const float* cls_w3  = (const float*)d_in[25];
  const float* cls_b3  = (const float*)d_in[26];

  float* ws = (float*)d_ws;
  // ---- workspace layout (float units) ----
  f16*   w1h   = (f16*)ws;                         // 589,824 f (conv1 B-frag)
  f16*   w2h   = (f16*)(ws + 589824);              // 2,359,296 f (conv2 B-frag; reused: h1h)
  f16*   mw2h  = (f16*)(ws + 2949120);             // 16,384 f
  f16*   saw2h = (f16*)(ws + 2965504);             // 4,096 f
  f16*   saw3h = (f16*)(ws + 2969600);             // 16,384 f
  f16*   saw4h = (f16*)(ws + 2985984);             // 65,536 f
  f16*   cw1h  = (f16*)(ws + 3051520);             // 524,288 f
  f16*   ctwh  = (f16*)(ws + 3575808);             // 1,048,576 f (B-frag layout)
  f16*   cw2h  = (f16*)(ws + 4624384);             // 131,072 f ([256][1024] fp16)
  float* obj   = ws + 4870144;                     // 16,384 f (adjacent to voxg -> one memset)
  float* big   = ws + 4886528;                     // 3,276,800 f (voxg, g1buf, g2buf, odw)
  f16*   voxh  = (f16*)(ws + 8163328);             // 819,200 f (reused: f2h)
  f16*   f1h   = (f16*)(ws + 8982528);             // 819,200 f
  f16*   scnh  = (f16*)(ws + 9801728);             // 1,638,400 f (reused: h2h)
  float* ocm   = ws + 11456512;                    // 64 f

  float* voxg  = big;                              // fp32 voxel merge buffer [32][400][256]
  f16*   g1buf = (f16*)big;                        // conv1 out (voxg dead after pack)
  f16*   g2buf = (f16*)big;                        // conv2 out (g1buf dead after pool1)
  f16*   f2h   = voxh;                             // pool2 out (voxh dead after conv1)
  f16*   h1h   = w2h;                              // cls1 out (w2h dead after conv2)
  f16*   h2h   = scnh;                             // cls2 out (scnh dead after cls1)
  float* odw   = big + 2097152;                    // 32,768 f (big dead after pool2)
  float* wab   = big + 2129920;                    // 2,048 f
  float* outp  = (float*)d_out;

  // single fused prep (all weight conversions + ocmean) + single memset (obj+voxg contiguous)
  hipMemsetAsync(obj, 0, (size_t)(16384 + 3276800) * 4, stream);
  prepfuse_k<<<3616, 256, 0, stream>>>(mlp_w2, sa_w2, sa_w3, sa_w4, cls_w2, cls_w1,
                                       convt_w, conv1_w, conv2_w, oc,
                                       mw2h, saw2h, saw3h, saw4h, cw2h, cw1h,
                                       ctwh, w1h, w2h, ocm);

  pointnet_lds_k<<<512, 512, 0, stream>>>(sc, mlp_w1, mlp_b1, mw2h, mlp_b2, voxg);
  cvt16_k<<<3200, 256, 0, stream>>>(voxg, voxh, 819200);

  convmfma_k<20, 20, 256, 512, 4><<<512, 256, 7 * 22 * 80, stream>>>(
      voxh, w1h, conv1_b, g1buf);
  pool1_k<<<3200, 256, 0, stream>>>(g1buf, f1h, scnh);
  convmfma_k<10, 10, 512, 1024, 2><<<512, 256, 7 * 12 * 80, stream>>>(
      f1h, w2h, conv2_b, g2buf);
  pool2_k<<<1600, 256, 0, stream>>>(g2buf, f2h);
  convt_mfma_k<<<512, 256, 0, stream>>>(f2h, ctwh, convt_b, scnh);

  sa_mfma_k<<<1024, 256, 0, stream>>>(oc, ocm, sa_w1, sa_b1, saw2h, sa_b2,
                                      saw3h, sa_b3, saw4h, sa_b4, obj);
  odprep_k<<<1024, 256, 0, stream>>>(obj, cls_w1, cls_b1, odw, wab);

  cls1_mfma_k<<<1024, 256, 0, stream>>>(scnh, odw, wab, pos, cw1h, h1h);
  cls2_mfma_k<<<128, 256, 0, stream>>>(h1h, cw2h, cls_b2, h2h);
  cls3_k<<<32, 128, 0, stream>>>(h2h, cls_w3, cls_b3, outp);
}

// Round 8
// 459.608 us; speedup vs baseline: 1.1430x; 1.0347x over previous
//
#include <hip/hip_runtime.h>

#define NB 32
#define PP 8192
#define OPP 2048

typedef _Float16 f16;
typedef f16 half8 __attribute__((ext_vector_type(8)));
typedef f16 half4 __attribute__((ext_vector_type(4)));
typedef f16 half2v __attribute__((ext_vector_type(2)));
typedef float f32x4 __attribute__((ext_vector_type(4)));

#define MFMA16(a, b, c) __builtin_amdgcn_mfma_f32_16x16x32_f16(a, b, c, 0, 0, 0)

// ======================= fused prep: all weight conversions + ocmean in ONE dispatch ===========
__global__ __launch_bounds__(256) void prepfuse_k(
    const float* __restrict__ mlp_w2, const float* __restrict__ sa_w2,
    const float* __restrict__ sa_w3, const float* __restrict__ sa_w4,
    const float* __restrict__ cls_w2, const float* __restrict__ cls_w1,
    const float* __restrict__ convt_w, const float* __restrict__ conv1_w,
    const float* __restrict__ conv2_w, const float* __restrict__ oc,
    f16* __restrict__ mw2h, f16* __restrict__ saw2h, f16* __restrict__ saw3h,
    f16* __restrict__ saw4h, f16* __restrict__ cw2h, f16* __restrict__ cw1h,
    f16* __restrict__ ctwh, f16* __restrict__ w1h, f16* __restrict__ w2h,
    float* __restrict__ ocm) {
  __shared__ float tile[512 * 9];          // 18,432 B (wfrag staging; reused by ocmean)
  int bb = blockIdx.x, t = threadIdx.x;
  if (bb < 2048) {
    constexpr int B0 = 8192, B1 = B0 + 2048, B2 = B1 + 8192, B3 = B2 + 32768, B4 = B3 + 65536;
    constexpr int C1e = B4 + 524288;       // cw1 float2 items
    constexpr int TOT = C1e + 2097152;     // ct scalar items
    for (int idx = bb * 256 + t; idx < TOT; idx += 2048 * 256) {
      if (idx < B4) {                      // five float4 -> half4 conversions
        const float* in; f16* out; int off;
        if (idx < B0)      { in = mlp_w2; out = mw2h;  off = idx; }
        else if (idx < B1) { in = sa_w2;  out = saw2h; off = idx - B0; }
        else if (idx < B2) { in = sa_w3;  out = saw3h; off = idx - B1; }
        else if (idx < B3) { in = sa_w4;  out = saw4h; off = idx - B2; }
        else               { in = cls_w2; out = cw2h;  off = idx - B3; }
        float4 v = ((const float4*)in)[off];
        half4 h; h.x = (f16)v.x; h.y = (f16)v.y; h.z = (f16)v.z; h.w = (f16)v.w;
        ((half4*)out)[off] = h;
      } else if (idx < C1e) {              // cls_w1 scene part [1024][1538] -> [1024][1024] fp16
        int i = idx - B4;
        int co = i >> 9, k2 = i & 511;
        float2 v = *(const float2*)(cls_w1 + (size_t)co * 1538 + k2 * 2);
        half2v h = {(f16)v.x, (f16)v.y};
        *(half2v*)(cw1h + (size_t)co * 1024 + k2 * 2) = h;
      } else {                             // convt_w -> MFMA B-fragment layout
        int i = idx - C1e;
        int j = i & 7, l = (i >> 3) & 63, kb = (i >> 9) & 31, nb = i >> 14;
        int n16 = l & 15, quad = l >> 4;
        int np = nb * 16 + n16;
        int k = kb * 32 + quad * 8 + j;
        int p = np >> 9, o = np & 511;
        ctwh[i] = (f16)convt_w[((size_t)o * 1024 + k) * 4 + (3 - p)];
      }
    }
  } else if (bb < 2080) {                  // ocmean
    float* sx = tile; float* sy = tile + 256;
    int n = bb - 2048;
    float ax = 0.f, ay = 0.f;
    for (int p = t; p < OPP; p += 256) {
      ax += oc[((size_t)n * OPP + p) * 2 + 0];
      ay += oc[((size_t)n * OPP + p) * 2 + 1];
    }
    sx[t] = ax; sy[t] = ay;
    __syncthreads();
    for (int s = 128; s > 0; s >>= 1) {
      if (t < s) { sx[t] += sx[t + s]; sy[t] += sy[t + s]; }
      __syncthreads();
    }
    if (t == 0) {
      ocm[n * 2 + 0] = sx[0] / (float)OPP;
      ocm[n * 2 + 1] = sy[0] / (float)OPP;
    }
  } else {                                 // conv wfrag (runtime-parameterized)
    int co, CI, NBB; const float* src0; f16* wf;
    if (bb < 2592) { co = bb - 2080; CI = 256; NBB = 32; src0 = conv1_w; wf = w1h; }
    else           { co = bb - 2592; CI = 512; NBB = 64; src0 = conv2_w; wf = w2h; }
    const float* src = src0 + (size_t)co * CI * 9;
    for (int i = t; i < CI * 9; i += 256) tile[i] = src[i];
    __syncthreads();
    int nb = co >> 4, l16c = co & 15;
    int tot = (CI / 32) * 9 * 4;
    for (int e = t; e < tot; e += 256) {
      int quad = e & 3;
      int kk = (e >> 2) % 9;
      int cic = e / 36;
      half8 v;
#pragma unroll
      for (int j = 0; j < 8; ++j) v[j] = (f16)tile[(cic * 32 + quad * 8 + j) * 9 + kk];
      *(half8*)(wf + ((((size_t)cic * 9 + kk) * NBB + nb) * 64 + quad * 16 + l16c) * 8) = v;
    }
  }
}

__global__ void cvt16_k(const float* __restrict__ in, f16* __restrict__ out, int n4) {
  int idx = blockIdx.x * 256 + threadIdx.x;
  if (idx >= n4) return;
  float4 v = ((const float4*)in)[idx];
  half4 h; h.x = (f16)v.x; h.y = (f16)v.y; h.z = (f16)v.z; h.w = (f16)v.w;
  ((half4*)out)[idx] = h;
}

// ======================= voxel PointNet: barrier-free LDS scatter-max =======================
// 256-thread blocks, grid = 32n * 8cg * 4ps = 1024. 2-point-per-lane ILP: each iteration
// carries TWO independent bin/layer1/MFMA/atomic chains so the scheduler can interleave.
__global__ __launch_bounds__(256) void pointnet_lds_k(
    const float* __restrict__ sc, const float* __restrict__ w1, const float* __restrict__ b1,
    const f16* __restrict__ w2h, const float* __restrict__ b2, float* __restrict__ voxg) {
  __shared__ float voxl[400 * 33];         // 52,800 B
  int t = threadIdx.x, lane = t & 63, w = t >> 6;
  int quad = lane >> 4, l16 = lane & 15;
  int b = blockIdx.x;
  int ps = b & 3, cg = (b >> 2) & 7, n = b >> 5;
  // packed layer-1 weights: this quad's 32 channels => 16 half2 per array
  half2v w1x2[16], w1y2[16], b12[16];
#pragma unroll
  for (int i = 0; i < 16; ++i) {
    int k0 = (i >> 2) * 32 + quad * 8 + (i & 3) * 2;   // ks = i>>2, j2 = i&3
    w1x2[i] = (half2v){(f16)w1[k0 * 2], (f16)w1[(k0 + 1) * 2]};
    w1y2[i] = (half2v){(f16)w1[k0 * 2 + 1], (f16)w1[(k0 + 1) * 2 + 1]};
    b12[i]  = (half2v){(f16)b1[k0], (f16)b1[k0 + 1]};
  }
  half8 bf[2][4];
  float bias[2];
#pragma unroll
  for (int nt = 0; nt < 2; ++nt) {
    int ch = cg * 32 + nt * 16 + l16;
    bias[nt] = b2[ch];
#pragma unroll
    for (int ks = 0; ks < 4; ++ks)
      bf[nt][ks] = *(const half8*)(w2h + (size_t)ch * 128 + ks * 32 + quad * 8);
  }
  for (int i = t; i < 400 * 33; i += 256) voxl[i] = 0.0f;
  __syncthreads();
  const half2v z2 = {};
  const float* scp = sc + ((size_t)n * PP + (size_t)ps * 2048) * 2;
  int p0 = w * 16 + l16;
  float2 xyA = *(const float2*)(scp + p0 * 2);
  float2 xyB = *(const float2*)(scp + (p0 + 64) * 2);
  for (int it = 0; it < 16; ++it) {
    float xA = xyA.x, yA = xyA.y, xB = xyB.x, yB = xyB.y;
    if (it < 15) {
      xyA = *(const float2*)(scp + ((it + 1) * 128 + p0) * 2);
      xyB = *(const float2*)(scp + ((it + 1) * 128 + p0 + 64) * 2);
    }
    // --- set A bin/offset ---
    float bifA = fminf(fmaxf(ceilf((xA + 0.5f) * 20.0f) - 1.0f, 0.0f), 19.0f);
    float bjfA = fminf(fmaxf(ceilf((yA + 0.5f) * 20.0f) - 1.0f, 0.0f), 19.0f);
    bool vA = (xA > -0.5f) && (xA <= 0.5f) && (yA > -0.5f) && (yA <= 0.5f);
    float pxA = xA - (-0.5f + (bifA + 0.5f) * 0.05f);
    float pyA = yA - (-0.5f + (bjfA + 0.5f) * 0.05f);
    int bnA = vA ? ((int)bifA * 20 + (int)bjfA) : -1;
    // --- set B bin/offset ---
    float bifB = fminf(fmaxf(ceilf((xB + 0.5f) * 20.0f) - 1.0f, 0.0f), 19.0f);
    float bjfB = fminf(fmaxf(ceilf((yB + 0.5f) * 20.0f) - 1.0f, 0.0f), 19.0f);
    bool vB = (xB > -0.5f) && (xB <= 0.5f) && (yB > -0.5f) && (yB <= 0.5f);
    float pxB = xB - (-0.5f + (bifB + 0.5f) * 0.05f);
    float pyB = yB - (-0.5f + (bjfB + 0.5f) * 0.05f);
    int bnB = vB ? ((int)bifB * 20 + (int)bjfB) : -1;
    f16 pxhA = (f16)pxA, pyhA = (f16)pyA, pxhB = (f16)pxB, pyhB = (f16)pyB;
    half2v px2A = (half2v){pxhA, pxhA}, py2A = (half2v){pyhA, pyhA};
    half2v px2B = (half2v){pxhB, pxhB}, py2B = (half2v){pyhB, pyhB};
    f32x4 acc0A = {}, acc1A = {}, acc0B = {}, acc1B = {};
#pragma unroll
    for (int ks = 0; ks < 4; ++ks) {
      half8 afA, afB;
#pragma unroll
      for (int j2 = 0; j2 < 4; ++j2) {
        half2v wx = w1x2[ks * 4 + j2], wy = w1y2[ks * 4 + j2], bb = b12[ks * 4 + j2];
        half2v tA = wx * px2A + (wy * py2A + bb);
        half2v tB = wx * px2B + (wy * py2B + bb);
        reinterpret_cast<half2v*>(&afA)[j2] = __builtin_elementwise_max(tA, z2);
        reinterpret_cast<half2v*>(&afB)[j2] = __builtin_elementwise_max(tB, z2);
      }
      acc0A = MFMA16(afA, bf[0][ks], acc0A);
      acc0B = MFMA16(afB, bf[0][ks], acc0B);
      acc1A = MFMA16(afA, bf[1][ks], acc1A);
      acc1B = MFMA16(afB, bf[1][ks], acc1B);
    }
#pragma unroll
    for (int r = 0; r < 4; ++r) {
      int bnA2 = __shfl(bnA, quad * 4 + r);
      int bnB2 = __shfl(bnB, quad * 4 + r);
      if (bnA2 >= 0) {
        float v0 = fmaxf(acc0A[r] + bias[0], 0.0f);
        float v1 = fmaxf(acc1A[r] + bias[1], 0.0f);
        atomicMax((int*)voxl + bnA2 * 33 + l16, __float_as_int(v0));
        atomicMax((int*)voxl + bnA2 * 33 + 16 + l16, __float_as_int(v1));
      }
      if (bnB2 >= 0) {
        float v0 = fmaxf(acc0B[r] + bias[0], 0.0f);
        float v1 = fmaxf(acc1B[r] + bias[1], 0.0f);
        atomicMax((int*)voxl + bnB2 * 33 + l16, __float_as_int(v0));
        atomicMax((int*)voxl + bnB2 * 33 + 16 + l16, __float_as_int(v1));
      }
    }
  }
  __syncthreads();
  // merge private LDS grid into the global fp32 voxel buffer
  float* vg = voxg + ((size_t)n * 400) * 256 + cg * 32;
  for (int i = t; i < 400 * 32; i += 256) {
    int bin = i >> 5, c = i & 31;
    float v = voxl[bin * 33 + c];
    if (v > 0.0f)
      atomicMax((int*)(vg + (size_t)bin * 256) + c, __float_as_int(v));
  }
}

// ======================= MFMA implicit-GEMM conv 3x3 pad1 + relu =======================
template <int H, int W, int CI, int CO, int MSPLIT>
__global__ __launch_bounds__(256, 2) void convmfma_k(
    const f16* __restrict__ inh, const f16* __restrict__ wf,
    const float* __restrict__ bias, f16* __restrict__ outh) {
  constexpr int HS = H / MSPLIT;
  constexpr int Mpix = HS * W;
  constexpr int MT = (Mpix + 15) / 16;
  constexpr int PR = HS + 2, PC = W + 2;
  constexpr int NCIC = CI / 32;
  constexpr int COG = CO / 128;
  constexpr int NBB = CO / 16;
  extern __shared__ char smem[];
  f16* Ap = (f16*)smem;                          // [PR*PC][40]
  int b = blockIdx.x;
  int cog = b % COG;
  int ms = (b / COG) % MSPLIT;
  int n = b / (COG * MSPLIT);
  int co0 = cog * 128;
  int r0 = ms * HS;
  int t = threadIdx.x, lane = t & 63, w = t >> 6;
  int quad = lane >> 4, l16 = lane & 15;
  int nb0 = cog * 8 + w * 2;                     // B-fragment row-block (16 co each)

  int abase[MT];
#pragma unroll
  for (int mi = 0; mi < MT; ++mi) {
    int pl = mi * 16 + l16; if (pl > Mpix - 1) pl = Mpix - 1;
    int y = pl / W, x = pl - y * W;
    abase[mi] = (y * PC + x) * 40 + quad * 8;    // halves
  }
  f32x4 acc[MT][2] = {};

  const f16* inbase = inh + (size_t)n * H * W * CI;

  for (int cic = 0; cic < NCIC; ++cic) {
    __syncthreads();                             // protect Ap from prior reads
    for (int cell = t; cell < PR * PC; cell += 256) {
      int pr = cell / PC, pc = cell - pr * PC;
      int yin = r0 - 1 + pr, xin = pc - 1;
      uint4 d0 = {0,0,0,0}, d1 = {0,0,0,0}, d2 = {0,0,0,0}, d3 = {0,0,0,0};
      if (yin >= 0 && yin < H && xin >= 0 && xin < W) {
        const uint4* src = (const uint4*)(inbase + ((size_t)yin * W + xin) * CI + cic * 32);
        d0 = src[0]; d1 = src[1]; d2 = src[2]; d3 = src[3];
      }
      uint4* dst = (uint4*)(Ap + cell * 40);
      dst[0] = d0; dst[1] = d1; dst[2] = d2; dst[3] = d3;
    }
    __syncthreads();
    const f16* wfc = wf + (size_t)(cic * 9) * NBB * 512;
#pragma unroll
    for (int ky = 0; ky < 3; ++ky)
#pragma unroll
      for (int kx = 0; kx < 3; ++kx) {
        int kk = ky * 3 + kx;
        half8 bf0 = *(const half8*)(wfc + ((size_t)(kk * NBB + nb0) * 64 + lane) * 8);
        half8 bf1 = *(const half8*)(wfc + ((size_t)(kk * NBB + nb0 + 1) * 64 + lane) * 8);
        int shift = (ky * PC + kx) * 40;
#pragma unroll
        for (int mi = 0; mi < MT; ++mi) {
          half8 af = *(const half8*)(Ap + abase[mi] + shift);
          acc[mi][0] = MFMA16(af, bf0, acc[mi][0]);
          acc[mi][1] = MFMA16(af, bf1, acc[mi][1]);
        }
      }
  }
  int co_w = co0 + w * 32;
  float bv0 = bias[co_w + l16];
  float bv1 = bias[co_w + 16 + l16];
  f16* ob = outh + ((size_t)n * H * W + (size_t)ms * Mpix) * CO;
#pragma unroll
  for (int mi = 0; mi < MT; ++mi) {
#pragma unroll
    for (int r = 0; r < 4; ++r) {
      int p = mi * 16 + quad * 4 + r;
      if (p < Mpix) {
        float v0 = acc[mi][0][r] + bv0; v0 = v0 > 0.f ? v0 : 0.f;
        float v1 = acc[mi][1][r] + bv1; v1 = v1 > 0.f ? v1 : 0.f;
        ob[(size_t)p * CO + co_w + l16] = (f16)v0;
        ob[(size_t)p * CO + co_w + 16 + l16] = (f16)v1;
      }
    }
  }
}

// ======================= maxpool 2x2 (+ fused pack into scene buffer) =======================
__global__ void pool1_k(const f16* __restrict__ g1, f16* __restrict__ f1h,
                        f16* __restrict__ scnh) {
  int idx = blockIdx.x * 256 + threadIdx.x;
  if (idx >= 32 * 100 * 256) return;
  int c2 = idx & 255, rem = idx >> 8;
  int op = rem % 100, n = rem / 100;
  int py = op / 10, px = op - py * 10;
  const f16* base = g1 + (((size_t)n * 400 + (size_t)(2 * py) * 20 + 2 * px) * 512) + c2 * 2;
  float a0 = (float)base[0],   a1 = (float)base[1];
  float b0 = (float)base[512], b1 = (float)base[513];
  const f16* base2 = base + 20 * 512;
  float c0 = (float)base2[0],   c1 = (float)base2[1];
  float d0 = (float)base2[512], d1 = (float)base2[513];
  union { f16 h[2]; unsigned u; } pk;
  pk.h[0] = (f16)fmaxf(fmaxf(a0, b0), fmaxf(c0, d0));
  pk.h[1] = (f16)fmaxf(fmaxf(a1, b1), fmaxf(c1, d1));
  *(unsigned*)(f1h + ((size_t)n * 100 + op) * 512 + c2 * 2) = pk.u;
  *(unsigned*)(scnh + ((size_t)n * 100 + op) * 1024 + c2 * 2) = pk.u;
}

__global__ void pool2_k(const f16* __restrict__ g2, f16* __restrict__ f2h) {
  int idx = blockIdx.x * 256 + threadIdx.x;
  if (idx >= 32 * 25 * 512) return;
  int c2 = idx & 511, rem = idx >> 9;
  int op = rem % 25, n = rem / 25;
  int py = op / 5, px = op - py * 5;
  const f16* base = g2 + (((size_t)n * 100 + (size_t)(2 * py) * 10 + 2 * px) * 1024) + c2 * 2;
  float a0 = (float)base[0],    a1 = (float)base[1];
  float b0 = (float)base[1024], b1 = (float)base[1025];
  const f16* base2 = base + 10 * 1024;
  float c0 = (float)base2[0],    c1 = (float)base2[1];
  float d0 = (float)base2[1024], d1 = (float)base2[1025];
  f16* o = f2h + ((size_t)n * 25 + op) * 1024 + c2 * 2;
  o[0] = (f16)fmaxf(fmaxf(a0, b0), fmaxf(c0, d0));
  o[1] = (f16)fmaxf(fmaxf(a1, b1), fmaxf(c1, d1));
}

// ======================= conv transpose 2x2 s2 (1024->512), MFMA v2 =======================
__global__ __launch_bounds__(256, 2) void convt_mfma_k(
    const f16* __restrict__ f2h, const f16* __restrict__ ctwf,
    const float* __restrict__ ctb, f16* __restrict__ scnh) {
  __shared__ f16 act[25 * 1048];           // 52,400 B
  int b = blockIdx.x;
  int ng = b & 15, n = b >> 4;
  int t = threadIdx.x, lane = t & 63, w = t >> 6;
  int quad = lane >> 4, l16 = lane & 15;
  for (int i = t; i < 25 * 128; i += 256) {
    int row = i >> 7, c8 = i & 127;
    *(half8*)(act + row * 1048 + c8 * 8) =
        *(const half8*)(f2h + ((size_t)n * 25 + row) * 1024 + c8 * 8);
  }
  __syncthreads();
  int r1 = 16 + (l16 > 8 ? 8 : l16);       // clamp: garbage rows never stored
  f32x4 acc[2][2] = {};
  const f16* wp0 = ctwf + ((size_t)((ng * 8 + w * 2 + 0) * 32) * 64 + lane) * 8;
  const f16* wp1 = ctwf + ((size_t)((ng * 8 + w * 2 + 1) * 32) * 64 + lane) * 8;
#pragma unroll 4
  for (int ks = 0; ks < 32; ++ks) {
    half8 a0 = *(const half8*)(act + l16 * 1048 + ks * 32 + quad * 8);
    half8 a1 = *(const half8*)(act + r1 * 1048 + ks * 32 + quad * 8);
    half8 b0 = *(const half8*)(wp0 + (size_t)ks * 512);
    half8 b1 = *(const half8*)(wp1 + (size_t)ks * 512);
    acc[0][0] = MFMA16(a0, b0, acc[0][0]);
    acc[1][0] = MFMA16(a1, b0, acc[1][0]);
    acc[0][1] = MFMA16(a0, b1, acc[0][1]);
    acc[1][1] = MFMA16(a1, b1, acc[1][1]);
  }
#pragma unroll
  for (int nt = 0; nt < 2; ++nt) {
    int np = ng * 128 + w * 32 + nt * 16 + l16;
    int p = np >> 9, co = np & 511;
    int a = p >> 1, bc = p & 1;
    float bb = ctb[co];
#pragma unroll
    for (int mt = 0; mt < 2; ++mt)
#pragma unroll
      for (int r = 0; r < 4; ++r) {
        int px = mt * 16 + quad * 4 + r;
        if (px < 25) {
          int ph = px / 5, pw = px - ph * 5;
          int opx = (2 * ph + a) * 10 + 2 * pw + bc;
          scnh[((size_t)n * 100 + opx) * 1024 + 512 + co] = (f16)(acc[mt][nt][r] + bb);
        }
      }
  }
}

// ======================= object SA: fused 4-layer MFMA + max (M=64 tiles) =======================
__global__ __launch_bounds__(256, 2) void sa_mfma_k(
    const float* __restrict__ oc, const float* __restrict__ ocm,
    const float* __restrict__ w1, const float* __restrict__ b1,
    const f16* __restrict__ w2h, const float* __restrict__ b2,
    const f16* __restrict__ w3h, const float* __restrict__ b3,
    const f16* __restrict__ w4h, const float* __restrict__ b4,
    float* __restrict__ obj) {
  __shared__ f16 act1[64 * 72];            // 9,216 B [pt][K=64]
  __shared__ f16 act2[64 * 136];           // 17,408 B [pt][K=128]
  __shared__ f16 act3[64 * 264];           // 33,792 B [pt][K=256]
  __shared__ float pcx[64], pcy[64];
  int b = blockIdx.x;                      // 1024 = 32 n * 32 chunks of 64 pts
  int n = b >> 5, pb = (b & 31) * 64;
  int t = threadIdx.x, lane = t & 63, w = t >> 6;
  int quad = lane >> 4, l16 = lane & 15;
  if (t < 64) {
    pcx[t] = oc[((size_t)n * OPP + pb + t) * 2 + 0] - ocm[n * 2 + 0];
    pcy[t] = oc[((size_t)n * OPP + pb + t) * 2 + 1] - ocm[n * 2 + 1];
  }
  __syncthreads();
  {                                        // layer1: 2 -> 64 for 64 points
    int c = t & 63, pg = t >> 6;
    float wx = w1[c * 2], wy = w1[c * 2 + 1], bb = b1[c];
#pragma unroll
    for (int j = 0; j < 16; ++j) {
      int p = pg * 16 + j;
      act1[p * 72 + c] = (f16)fmaxf(fmaf(wx, pcx[p], fmaf(wy, pcy[p], bb)), 0.0f);
    }
  }
  __syncthreads();
  {                                        // layer2: M=64, K=64, N=128; wave n-range 32
    int n0 = w * 32;
    f32x4 acc[4][2] = {};
#pragma unroll
    for (int ks = 0; ks < 2; ++ks) {
      half8 a[4];
#pragma unroll
      for (int mt = 0; mt < 4; ++mt)
        a[mt] = *(const half8*)(act1 + (mt * 16 + l16) * 72 + ks * 32 + quad * 8);
#pragma unroll
      for (int nt = 0; nt < 2; ++nt) {
        half8 bf = *(const half8*)(w2h + (size_t)(n0 + nt * 16 + l16) * 64 + ks * 32 + quad * 8);
#pragma unroll
        for (int mt = 0; mt < 4; ++mt)
          acc[mt][nt] = MFMA16(a[mt], bf, acc[mt][nt]);
      }
    }
#pragma unroll
    for (int nt = 0; nt < 2; ++nt) {
      int col = n0 + nt * 16 + l16;
      float bb = b2[col];
#pragma unroll
      for (int mt = 0; mt < 4; ++mt)
#pragma unroll
        for (int r = 0; r < 4; ++r)
          act2[(mt * 16 + quad * 4 + r) * 136 + col] = (f16)fmaxf(acc[mt][nt][r] + bb, 0.0f);
    }
  }
  __syncthreads();
  {                                        // layer3: M=64, K=128, N=256; wave n-range 64
    int n0 = w * 64;
    f32x4 acc[4][4] = {};
#pragma unroll
    for (int ks = 0; ks < 4; ++ks) {
      half8 a[4];
#pragma unroll
      for (int mt = 0; mt < 4; ++mt)
        a[mt] = *(const half8*)(act2 + (mt * 16 + l16) * 136 + ks * 32 + quad * 8);
#pragma unroll
      for (int nt = 0; nt < 4; ++nt) {
        half8 bf = *(const half8*)(w3h + (size_t)(n0 + nt * 16 + l16) * 128 + ks * 32 + quad * 8);
#pragma unroll
        for (int mt = 0; mt < 4; ++mt)
          acc[mt][nt] = MFMA16(a[mt], bf, acc[mt][nt]);
      }
    }
#pragma unroll
    for (int nt = 0; nt < 4; ++nt) {
      int col = n0 + nt * 16 + l16;
      float bb = b3[col];
#pragma unroll
      for (int mt = 0; mt < 4; ++mt)
#pragma unroll
        for (int r = 0; r < 4; ++r)
          act3[(mt * 16 + quad * 4 + r) * 264 + col] = (f16)fmaxf(acc[mt][nt][r] + bb, 0.0f);
    }
  }
  __syncthreads();
  {                                        // layer4: M=64, K=256, N=512; wave n-range 128; + max
    int n0 = w * 128;
    f32x4 acc[4][8] = {};
#pragma unroll
    for (int ks = 0; ks < 8; ++ks) {
      half8 a[4];
#pragma unroll
      for (int mt = 0; mt < 4; ++mt)
        a[mt] = *(const half8*)(act3 + (mt * 16 + l16) * 264 + ks * 32 + quad * 8);
#pragma unroll
      for (int nt = 0; nt < 8; ++nt) {
        half8 bf = *(const half8*)(w4h + (size_t)(n0 + nt * 16 + l16) * 256 + ks * 32 + quad * 8);
#pragma unroll
        for (int mt = 0; mt < 4; ++mt)
          acc[mt][nt] = MFMA16(a[mt], bf, acc[mt][nt]);
      }
    }
#pragma unroll
    for (int nt = 0; nt < 8; ++nt) {
      int col = n0 + nt * 16 + l16;
      float bb = b4[col];
      float v = 0.0f;
#pragma unroll
      for (int mt = 0; mt < 4; ++mt)
#pragma unroll
        for (int r = 0; r < 4; ++r)
          v = fmaxf(v, acc[mt][nt][r] + bb);
      v = fmaxf(v, 0.0f);
      v = fmaxf(v, __shfl_xor(v, 16));
      v = fmaxf(v, __shfl_xor(v, 32));
      if (quad == 0)
        atomicMax((int*)obj + (size_t)n * 512 + col, __float_as_int(v));
    }
  }
}

// ======================= obj-dot precompute: odw[n][co] = obj[n]·w1raw[co,1024:1536] + b1 =======
__global__ __launch_bounds__(256) void odprep_k(
    const float* __restrict__ obj, const float* __restrict__ w1raw,
    const float* __restrict__ b1, float* __restrict__ odw, float* __restrict__ wab) {
  int co = blockIdx.x;
  int t = threadIdx.x, lane = t & 63, w = t >> 6;
  const float* wr = w1raw + (size_t)co * 1538 + 1024;
  float2 wv[4];
#pragma unroll
  for (int j = 0; j < 4; ++j) wv[j] = *(const float2*)(wr + lane * 8 + j * 2);
  float bb = b1[co];
  for (int i = 0; i < 8; ++i) {
    int n = w * 8 + i;
    const float* ob = obj + (size_t)n * 512 + lane * 8;
    float od = 0.0f;
#pragma unroll
    for (int j = 0; j < 4; ++j) {
      float2 ov = *(const float2*)(ob + j * 2);
      od = fmaf(wv[j].x, ov.x, od);
      od = fmaf(wv[j].y, ov.y, od);
    }
    od += __shfl_xor(od, 1);  od += __shfl_xor(od, 2);
    od += __shfl_xor(od, 4);  od += __shfl_xor(od, 8);
    od += __shfl_xor(od, 16); od += __shfl_xor(od, 32);
    if (lane == 0) odw[(size_t)n * 1024 + co] = od + bb;
  }
  if (t == 0) { wab[co * 2] = wr[512]; wab[co * 2 + 1] = wr[513]; }
}

// ======================= classifier layer 1 (1538 -> 1024), MFMA =======================
// grid = 1024; o8 = b&7 so all blocks sharing a w1h octant slice land on ONE XCD.
__global__ __launch_bounds__(256) void cls1_mfma_k(
    const f16* __restrict__ scnh, const float* __restrict__ odw,
    const float* __restrict__ wab, const float* __restrict__ pos,
    const f16* __restrict__ w1h, f16* __restrict__ h1h) {
  __shared__ f16 act[25 * 1032];           // 51,600 B
  __shared__ float odl[128], wAl[128], wBl[128];
  int b = blockIdx.x;
  int o8 = b & 7, mq = (b >> 3) & 3, n = b >> 5;
  int co0 = o8 * 128, p0 = mq * 25;
  int t = threadIdx.x, lane = t & 63, w = t >> 6;
  int quad = lane >> 4, l16 = lane & 15;
  for (int i = t; i < 25 * 128; i += 256) {
    int row = i >> 7, c8 = i & 127;
    *(half8*)(act + row * 1032 + c8 * 8) =
        *(const half8*)(scnh + ((size_t)n * 100 + p0 + row) * 1024 + c8 * 8);
  }
  if (t < 128) {
    odl[t] = odw[(size_t)n * 1024 + co0 + t];
    float2 ab = *(const float2*)(wab + (size_t)(co0 + t) * 2);
    wAl[t] = ab.x; wBl[t] = ab.y;
  }
  __syncthreads();
  float posx = pos[n * 2 + 0], posy = pos[n * 2 + 1];
  f32x4 acc[2][2];
#pragma unroll
  for (int mt = 0; mt < 2; ++mt)
#pragma unroll
    for (int nt = 0; nt < 2; ++nt) {
      int cl = w * 32 + nt * 16 + l16;
      float od = odl[cl], wA = wAl[cl], wB = wBl[cl];
#pragma unroll
      for (int r = 0; r < 4; ++r) {
        int pl = mt * 16 + quad * 4 + r;
        int px = p0 + (pl < 25 ? pl : 24);         // clamped lanes never stored
        float relx = posx - (-0.5f + ((px / 10) + 0.5f) * 0.1f);
        float rely = posy - (-0.5f + ((px % 10) + 0.5f) * 0.1f);
        acc[mt][nt][r] = od + relx * wA + rely * wB;
      }
    }
  int gr0 = l16;
  int gr1 = (16 + l16 > 24) ? 24 : 16 + l16;
  const f16* wb0 = w1h + (size_t)(co0 + w * 32 + l16) * 1024 + quad * 8;
  const f16* wb1 = wb0 + (size_t)16 * 1024;
#pragma unroll 4
  for (int kq = 0; kq < 32; ++kq) {
    int k0 = kq * 32;
    half8 bf0 = *(const half8*)(wb0 + k0);
    half8 bf1 = *(const half8*)(wb1 + k0);
    half8 a0 = *(const half8*)(act + gr0 * 1032 + k0 + quad * 8);
    half8 a1 = *(const half8*)(act + gr1 * 1032 + k0 + quad * 8);
    acc[0][0] = MFMA16(a0, bf0, acc[0][0]);
    acc[1][0] = MFMA16(a1, bf0, acc[1][0]);
    acc[0][1] = MFMA16(a0, bf1, acc[0][1]);
    acc[1][1] = MFMA16(a1, bf1, acc[1][1]);
  }
#pragma unroll
  for (int mt = 0; mt < 2; ++mt)
#pragma unroll
    for (int nt = 0; nt < 2; ++nt) {
      int co = co0 + w * 32 + nt * 16 + l16;
#pragma unroll
      for (int r = 0; r < 4; ++r) {
        int pl = mt * 16 + quad * 4 + r;
        if (pl < 25)
          h1h[((size_t)n * 100 + p0 + pl) * 1024 + co] = (f16)fmaxf(acc[mt][nt][r], 0.0f);
      }
    }
}

// ======================= classifier layer 2 (1024 -> 256), MFMA, barrier-free =======================
// grid = 256 = 32 n * 2 ng * 4 mq (25-px tiles); act staged once, no in-loop barriers.
__global__ __launch_bounds__(256) void cls2_mfma_k(
    const f16* __restrict__ h1h, const f16* __restrict__ w2h16,
    const float* __restrict__ b2, f16* __restrict__ h2h) {
  __shared__ f16 act[25 * 1032];           // 51,600 B
  int b = blockIdx.x;
  int ng = b & 1, mq = (b >> 1) & 3, n = b >> 3;
  int co0 = ng * 128, p0 = mq * 25;
  int t = threadIdx.x, lane = t & 63, w = t >> 6;
  int quad = lane >> 4, l16 = lane & 15;
  for (int i = t; i < 25 * 128; i += 256) {
    int row = i >> 7, c8 = i & 127;
    *(half8*)(act + row * 1032 + c8 * 8) =
        *(const half8*)(h1h + ((size_t)n * 100 + p0 + row) * 1024 + c8 * 8);
  }
  __syncthreads();
  f32x4 acc[2][2] = {};
  int gr0 = l16;
  int gr1 = (16 + l16 > 24) ? 24 : 16 + l16;     // clamped rows never stored
  const f16* wb0 = w2h16 + (size_t)(co0 + w * 32 + l16) * 1024 + quad * 8;
  const f16* wb1 = wb0 + (size_t)16 * 1024;
#pragma unroll 4
  for (int kq = 0; kq < 32; ++kq) {
    int k0 = kq * 32;
    half8 bf0 = *(const half8*)(wb0 + k0);
    half8 bf1 = *(const half8*)(wb1 + k0);
    half8 a0 = *(const half8*)(act + gr0 * 1032 + k0 + quad * 8);
    half8 a1 = *(const half8*)(act + gr1 * 1032 + k0 + quad * 8);
    acc[0][0] = MFMA16(a0, bf0, acc[0][0]);
    acc[1][0] = MFMA16(a1, bf0, acc[1][0]);
    acc[0][1] = MFMA16(a0, bf1, acc[0][1]);
    acc[1][1] = MFMA16(a1, bf1, acc[1][1]);
  }
#pragma unroll
  for (int mt = 0; mt < 2; ++mt)
#pragma unroll
    for (int nt = 0; nt < 2; ++nt) {
      int co = co0 + w * 32 + nt * 16 + l16;
      float bb = b2[co];
#pragma unroll
      for (int r = 0; r < 4; ++r) {
        int pl = mt * 16 + quad * 4 + r;
        if (pl < 25)
          h2h[((size_t)n * 100 + p0 + pl) * 256 + co] = (f16)fmaxf(acc[mt][nt][r] + bb, 0.0f);
      }
    }
}

// ======================= classifier layer 3 (256 -> 1) =======================
__global__ void cls3_k(const f16* __restrict__ h2h, const float* __restrict__ w3,
                       const float* __restrict__ b3, float* __restrict__ out) {
  int n = blockIdx.x, t = threadIdx.x;
  if (t < 100) {
    float acc = b3[0];
    const f16* hp = &h2h[((size_t)n * 100 + t) * 256];
    for (int k = 0; k < 256; ++k) acc = fmaf((float)hp[k], w3[k], acc);
    out[n * 100 + t] = acc;
  }
}

// ======================= launch =======================
extern "C" void kernel_launch(void* const* d_in, const int* in_sizes, int n_in,
                              void* d_out, int out_size, void* d_ws, size_t ws_size,
                              hipStream_t stream) {
  const float* sc      = (const float*)d_in[0];
  const float* oc      = (const float*)d_in[1];
  const float* pos     = (const float*)d_in[2];
  const float* mlp_w1  = (const float*)d_in[3];
  const float* mlp_b1  = (const float*)d_in[4];
  const float* mlp_w2  = (const float*)d_in[5];
  const float* mlp_b2  = (const float*)d_in[6];
  const float* conv1_w = (const float*)d_in[7];
  const float* conv1_b = (const float*)d_in[8];
  const float* conv2_w = (const float*)d_in[9];
  const float* conv2_b = (const float*)d_in[10];
  const float* convt_w = (const float*)d_in[11];
  const float* convt_b = (const float*)d_in[12];
  const float* sa_w1   = (const float*)d_in[13];
  const float* sa_b1   = (const float*)d_in[14];
  const float* sa_w2   = (const float*)d_in[15];
  const float* sa_b2   = (const float*)d_in[16];
  const float* sa_w3   = (const float*)d_in[17];
  const float* sa_b3   = (const float*)d_in[18];
  const float* sa_w4   = (const float*)d_in[19];
  const float* sa_b4   = (const float*)d_in[20];
  const float* cls_w1  = (const float*)d_in[21];
  const float* cls_b1  = (const float*)d_in[22];
  const float* cls_w2  = (const float*)d_in[23];
  const float* cls_b2  = (const float*)d_in[24];
  const float* cls_w3  = (const float*)d_in[25];
  const float* cls_b3  = (const float*)d_in[26];

  float* ws = (float*)d_ws;
  // ---- workspace layout (float units) ----
  f16*   w1h   = (f16*)ws;                         // 589,824 f (conv1 B-frag)
  f16*   w2h   = (f16*)(ws + 589824);              // 2,359,296 f (conv2 B-frag; reused: h1h)
  f16*   mw2h  = (f16*)(ws + 2949120);             // 16,384 f
  f16*   saw2h = (f16*)(ws + 2965504);             // 4,096 f
  f16*   saw3h = (f16*)(ws + 2969600);             // 16,384 f
  f16*   saw4h = (f16*)(ws + 2985984);             // 65,536 f
  f16*   cw1h  = (f16*)(ws + 3051520);             // 524,288 f
  f16*   ctwh  = (f16*)(ws + 3575808);             // 1,048,576 f (B-frag layout)
  f16*   cw2h  = (f16*)(ws + 4624384);             // 131,072 f ([256][1024] fp16)
  float* obj   = ws + 4870144;                     // 16,384 f (adjacent to voxg -> one memset)
  float* big   = ws + 4886528;                     // 3,276,800 f (voxg, g1buf, g2buf, odw)
  f16*   voxh  = (f16*)(ws + 8163328);             // 819,200 f (reused: f2h)
  f16*   f1h   = (f16*)(ws + 8982528);             // 819,200 f
  f16*   scnh  = (f16*)(ws + 9801728);             // 1,638,400 f (reused: h2h)
  float* ocm   = ws + 11456512;                    // 64 f

  float* voxg  = big;                              // fp32 voxel merge buffer [32][400][256]
  f16*   g1buf = (f16*)big;                        // conv1 out (voxg dead after pack)
  f16*   g2buf = (f16*)big;                        // conv2 out (g1buf dead after pool1)
  f16*   f2h   = voxh;                             // pool2 out (voxh dead after conv1)
  f16*   h1h   = w2h;                              // cls1 out (w2h dead after conv2)
  f16*   h2h   = scnh;                             // cls2 out (scnh dead after cls1)
  float* odw   = big + 2097152;                    // 32,768 f (big dead after pool2)
  float* wab   = big + 2129920;                    // 2,048 f
  float* outp  = (float*)d_out;

  // single fused prep (all weight conversions + ocmean) + single memset (obj+voxg contiguous)
  hipMemsetAsync(obj, 0, (size_t)(16384 + 3276800) * 4, stream);
  prepfuse_k<<<3616, 256, 0, stream>>>(mlp_w2, sa_w2, sa_w3, sa_w4, cls_w2, cls_w1,
                                       convt_w, conv1_w, conv2_w, oc,
                                       mw2h, saw2h, saw3h, saw4h, cw2h, cw1h,
                                       ctwh, w1h, w2h, ocm);

  pointnet_lds_k<<<1024, 256, 0, stream>>>(sc, mlp_w1, mlp_b1, mw2h, mlp_b2, voxg);
  cvt16_k<<<3200, 256, 0, stream>>>(voxg, voxh, 819200);

  convmfma_k<20, 20, 256, 512, 4><<<512, 256, 7 * 22 * 80, stream>>>(
      voxh, w1h, conv1_b, g1buf);
  pool1_k<<<3200, 256, 0, stream>>>(g1buf, f1h, scnh);
  convmfma_k<10, 10, 512, 1024, 2><<<512, 256, 7 * 12 * 80, stream>>>(
      f1h, w2h, conv2_b, g2buf);
  pool2_k<<<1600, 256, 0, stream>>>(g2buf, f2h);
  convt_mfma_k<<<512, 256, 0, stream>>>(f2h, ctwh, convt_b, scnh);

  sa_mfma_k<<<1024, 256, 0, stream>>>(oc, ocm, sa_w1, sa_b1, saw2h, sa_b2,
                                      saw3h, sa_b3, saw4h, sa_b4, obj);
  odprep_k<<<1024, 256, 0, stream>>>(obj, cls_w1, cls_b1, odw, wab);

  cls1_mfma_k<<<1024, 256, 0, stream>>>(scnh, odw, wab, pos, cw1h, h1h);
  cls2_mfma_k<<<256, 256, 0, stream>>>(h1h, cw2h, cls_b2, h2h);
  cls3_k<<<32, 128, 0, stream>>>(h2h, cls_w3, cls_b3, outp);
}

// Round 9
// 440.854 us; speedup vs baseline: 1.1917x; 1.0425x over previous
//
#include <hip/hip_runtime.h>

#define NB 32
#define PP 8192
#define OPP 2048

typedef _Float16 f16;
typedef f16 half8 __attribute__((ext_vector_type(8)));
typedef f16 half4 __attribute__((ext_vector_type(4)));
typedef f16 half2v __attribute__((ext_vector_type(2)));
typedef float f32x4 __attribute__((ext_vector_type(4)));

#define MFMA16(a, b, c) __builtin_amdgcn_mfma_f32_16x16x32_f16(a, b, c, 0, 0, 0)

// ======================= fused prep: all weight conversions + ocmean in ONE dispatch ===========
__global__ __launch_bounds__(256) void prepfuse_k(
    const float* __restrict__ mlp_w2, const float* __restrict__ sa_w2,
    const float* __restrict__ sa_w3, const float* __restrict__ sa_w4,
    const float* __restrict__ cls_w2, const float* __restrict__ cls_w1,
    const float* __restrict__ convt_w, const float* __restrict__ conv1_w,
    const float* __restrict__ conv2_w, const float* __restrict__ oc,
    f16* __restrict__ mw2h, f16* __restrict__ saw2h, f16* __restrict__ saw3h,
    f16* __restrict__ saw4h, f16* __restrict__ cw2h, f16* __restrict__ cw1h,
    f16* __restrict__ ctwh, f16* __restrict__ w1h, f16* __restrict__ w2h,
    float* __restrict__ ocm) {
  __shared__ float tile[512 * 9];          // 18,432 B (wfrag staging; reused by ocmean)
  int bb = blockIdx.x, t = threadIdx.x;
  if (bb < 2048) {
    constexpr int B0 = 8192, B1 = B0 + 2048, B2 = B1 + 8192, B3 = B2 + 32768, B4 = B3 + 65536;
    constexpr int C1e = B4 + 524288;       // cw1 float2 items
    constexpr int TOT = C1e + 2097152;     // ct scalar items
    for (int idx = bb * 256 + t; idx < TOT; idx += 2048 * 256) {
      if (idx < B4) {                      // five float4 -> half4 conversions
        const float* in; f16* out; int off;
        if (idx < B0)      { in = mlp_w2; out = mw2h;  off = idx; }
        else if (idx < B1) { in = sa_w2;  out = saw2h; off = idx - B0; }
        else if (idx < B2) { in = sa_w3;  out = saw3h; off = idx - B1; }
        else if (idx < B3) { in = sa_w4;  out = saw4h; off = idx - B2; }
        else               { in = cls_w2; out = cw2h;  off = idx - B3; }
        float4 v = ((const float4*)in)[off];
        half4 h; h.x = (f16)v.x; h.y = (f16)v.y; h.z = (f16)v.z; h.w = (f16)v.w;
        ((half4*)out)[off] = h;
      } else if (idx < C1e) {              // cls_w1 scene part [1024][1538] -> [1024][1024] fp16
        int i = idx - B4;
        int co = i >> 9, k2 = i & 511;
        float2 v = *(const float2*)(cls_w1 + (size_t)co * 1538 + k2 * 2);
        half2v h = {(f16)v.x, (f16)v.y};
        *(half2v*)(cw1h + (size_t)co * 1024 + k2 * 2) = h;
      } else {                             // convt_w -> MFMA B-fragment layout
        int i = idx - C1e;
        int j = i & 7, l = (i >> 3) & 63, kb = (i >> 9) & 31, nb = i >> 14;
        int n16 = l & 15, quad = l >> 4;
        int np = nb * 16 + n16;
        int k = kb * 32 + quad * 8 + j;
        int p = np >> 9, o = np & 511;
        ctwh[i] = (f16)convt_w[((size_t)o * 1024 + k) * 4 + (3 - p)];
      }
    }
  } else if (bb < 2080) {                  // ocmean
    float* sx = tile; float* sy = tile + 256;
    int n = bb - 2048;
    float ax = 0.f, ay = 0.f;
    for (int p = t; p < OPP; p += 256) {
      ax += oc[((size_t)n * OPP + p) * 2 + 0];
      ay += oc[((size_t)n * OPP + p) * 2 + 1];
    }
    sx[t] = ax; sy[t] = ay;
    __syncthreads();
    for (int s = 128; s > 0; s >>= 1) {
      if (t < s) { sx[t] += sx[t + s]; sy[t] += sy[t + s]; }
      __syncthreads();
    }
    if (t == 0) {
      ocm[n * 2 + 0] = sx[0] / (float)OPP;
      ocm[n * 2 + 1] = sy[0] / (float)OPP;
    }
  } else {                                 // conv wfrag (runtime-parameterized)
    int co, CI, NBB; const float* src0; f16* wf;
    if (bb < 2592) { co = bb - 2080; CI = 256; NBB = 32; src0 = conv1_w; wf = w1h; }
    else           { co = bb - 2592; CI = 512; NBB = 64; src0 = conv2_w; wf = w2h; }
    const float* src = src0 + (size_t)co * CI * 9;
    for (int i = t; i < CI * 9; i += 256) tile[i] = src[i];
    __syncthreads();
    int nb = co >> 4, l16c = co & 15;
    int tot = (CI / 32) * 9 * 4;
    for (int e = t; e < tot; e += 256) {
      int quad = e & 3;
      int kk = (e >> 2) % 9;
      int cic = e / 36;
      half8 v;
#pragma unroll
      for (int j = 0; j < 8; ++j) v[j] = (f16)tile[(cic * 32 + quad * 8 + j) * 9 + kk];
      *(half8*)(wf + ((((size_t)cic * 9 + kk) * NBB + nb) * 64 + quad * 16 + l16c) * 8) = v;
    }
  }
}

// ======================= voxel PointNet: barrier-free LDS scatter-max =======================
// 256-thread blocks, grid = 1024; 2-point-per-lane ILP.
__global__ __launch_bounds__(256) void pointnet_lds_k(
    const float* __restrict__ sc, const float* __restrict__ w1, const float* __restrict__ b1,
    const f16* __restrict__ w2h, const float* __restrict__ b2, float* __restrict__ voxg) {
  __shared__ float voxl[400 * 33];         // 52,800 B
  int t = threadIdx.x, lane = t & 63, w = t >> 6;
  int quad = lane >> 4, l16 = lane & 15;
  int b = blockIdx.x;
  int ps = b & 3, cg = (b >> 2) & 7, n = b >> 5;
  half2v w1x2[16], w1y2[16], b12[16];
#pragma unroll
  for (int i = 0; i < 16; ++i) {
    int k0 = (i >> 2) * 32 + quad * 8 + (i & 3) * 2;
    w1x2[i] = (half2v){(f16)w1[k0 * 2], (f16)w1[(k0 + 1) * 2]};
    w1y2[i] = (half2v){(f16)w1[k0 * 2 + 1], (f16)w1[(k0 + 1) * 2 + 1]};
    b12[i]  = (half2v){(f16)b1[k0], (f16)b1[k0 + 1]};
  }
  half8 bf[2][4];
  float bias[2];
#pragma unroll
  for (int nt = 0; nt < 2; ++nt) {
    int ch = cg * 32 + nt * 16 + l16;
    bias[nt] = b2[ch];
#pragma unroll
    for (int ks = 0; ks < 4; ++ks)
      bf[nt][ks] = *(const half8*)(w2h + (size_t)ch * 128 + ks * 32 + quad * 8);
  }
  for (int i = t; i < 400 * 33; i += 256) voxl[i] = 0.0f;
  __syncthreads();
  const half2v z2 = {};
  const float* scp = sc + ((size_t)n * PP + (size_t)ps * 2048) * 2;
  int p0 = w * 16 + l16;
  float2 xyA = *(const float2*)(scp + p0 * 2);
  float2 xyB = *(const float2*)(scp + (p0 + 64) * 2);
  for (int it = 0; it < 16; ++it) {
    float xA = xyA.x, yA = xyA.y, xB = xyB.x, yB = xyB.y;
    if (it < 15) {
      xyA = *(const float2*)(scp + ((it + 1) * 128 + p0) * 2);
      xyB = *(const float2*)(scp + ((it + 1) * 128 + p0 + 64) * 2);
    }
    float bifA = fminf(fmaxf(ceilf((xA + 0.5f) * 20.0f) - 1.0f, 0.0f), 19.0f);
    float bjfA = fminf(fmaxf(ceilf((yA + 0.5f) * 20.0f) - 1.0f, 0.0f), 19.0f);
    bool vA = (xA > -0.5f) && (xA <= 0.5f) && (yA > -0.5f) && (yA <= 0.5f);
    float pxA = xA - (-0.5f + (bifA + 0.5f) * 0.05f);
    float pyA = yA - (-0.5f + (bjfA + 0.5f) * 0.05f);
    int bnA = vA ? ((int)bifA * 20 + (int)bjfA) : -1;
    float bifB = fminf(fmaxf(ceilf((xB + 0.5f) * 20.0f) - 1.0f, 0.0f), 19.0f);
    float bjfB = fminf(fmaxf(ceilf((yB + 0.5f) * 20.0f) - 1.0f, 0.0f), 19.0f);
    bool vB = (xB > -0.5f) && (xB <= 0.5f) && (yB > -0.5f) && (yB <= 0.5f);
    float pxB = xB - (-0.5f + (bifB + 0.5f) * 0.05f);
    float pyB = yB - (-0.5f + (bjfB + 0.5f) * 0.05f);
    int bnB = vB ? ((int)bifB * 20 + (int)bjfB) : -1;
    f16 pxhA = (f16)pxA, pyhA = (f16)pyA, pxhB = (f16)pxB, pyhB = (f16)pyB;
    half2v px2A = (half2v){pxhA, pxhA}, py2A = (half2v){pyhA, pyhA};
    half2v px2B = (half2v){pxhB, pxhB}, py2B = (half2v){pyhB, pyhB};
    f32x4 acc0A = {}, acc1A = {}, acc0B = {}, acc1B = {};
#pragma unroll
    for (int ks = 0; ks < 4; ++ks) {
      half8 afA, afB;
#pragma unroll
      for (int j2 = 0; j2 < 4; ++j2) {
        half2v wx = w1x2[ks * 4 + j2], wy = w1y2[ks * 4 + j2], bb = b12[ks * 4 + j2];
        half2v tA = wx * px2A + (wy * py2A + bb);
        half2v tB = wx * px2B + (wy * py2B + bb);
        reinterpret_cast<half2v*>(&afA)[j2] = __builtin_elementwise_max(tA, z2);
        reinterpret_cast<half2v*>(&afB)[j2] = __builtin_elementwise_max(tB, z2);
      }
      acc0A = MFMA16(afA, bf[0][ks], acc0A);
      acc0B = MFMA16(afB, bf[0][ks], acc0B);
      acc1A = MFMA16(afA, bf[1][ks], acc1A);
      acc1B = MFMA16(afB, bf[1][ks], acc1B);
    }
#pragma unroll
    for (int r = 0; r < 4; ++r) {
      int bnA2 = __shfl(bnA, quad * 4 + r);
      int bnB2 = __shfl(bnB, quad * 4 + r);
      if (bnA2 >= 0) {
        float v0 = fmaxf(acc0A[r] + bias[0], 0.0f);
        float v1 = fmaxf(acc1A[r] + bias[1], 0.0f);
        atomicMax((int*)voxl + bnA2 * 33 + l16, __float_as_int(v0));
        atomicMax((int*)voxl + bnA2 * 33 + 16 + l16, __float_as_int(v1));
      }
      if (bnB2 >= 0) {
        float v0 = fmaxf(acc0B[r] + bias[0], 0.0f);
        float v1 = fmaxf(acc1B[r] + bias[1], 0.0f);
        atomicMax((int*)voxl + bnB2 * 33 + l16, __float_as_int(v0));
        atomicMax((int*)voxl + bnB2 * 33 + 16 + l16, __float_as_int(v1));
      }
    }
  }
  __syncthreads();
  float* vg = voxg + ((size_t)n * 400) * 256 + cg * 32;
  for (int i = t; i < 400 * 32; i += 256) {
    int bin = i >> 5, c = i & 31;
    float v = voxl[bin * 33 + c];
    if (v > 0.0f)
      atomicMax((int*)(vg + (size_t)bin * 256) + c, __float_as_int(v));
  }
}

// ======================= MFMA implicit-GEMM conv 3x3 pad1 + relu + FUSED 2x2 maxpool ==========
// HS=2 per block (one pool row); grid = n * MSPLIT * COG = 1280 (5 blocks/CU).
// INF32: input is fp32 (voxg) converted to f16 during staging (replaces cvt16 pass).
// WR2: also write pooled output into scene buffer (stride 1024).
template <int H, int W, int CI, int CO, int MSPLIT, bool INF32, bool WR2>
__global__ __launch_bounds__(256) void convpool_k(
    const void* __restrict__ inv, const f16* __restrict__ wf,
    const float* __restrict__ bias, f16* __restrict__ out1, f16* __restrict__ out2) {
  constexpr int HS = H / MSPLIT;                 // 2
  constexpr int Mpix = HS * W;
  constexpr int MT = (Mpix + 15) / 16;
  constexpr int PR = HS + 2, PC = W + 2;
  constexpr int NCIC = CI / 32;
  constexpr int COG = CO / 128;
  constexpr int NBB = CO / 16;
  constexpr int PW = W / 2;
  constexpr int POPS = (H / 2) * (W / 2);
  extern __shared__ char smem[];
  f16* Ap = (f16*)smem;                          // [PR*PC][40] halves
  f16* pb = (f16*)smem;                          // reused after barrier: [Mpix][136]
  int b = blockIdx.x;
  int cog = b % COG;
  int ms = (b / COG) % MSPLIT;
  int n = b / (COG * MSPLIT);
  int co0 = cog * 128;
  int r0 = ms * HS;
  int t = threadIdx.x, lane = t & 63, w = t >> 6;
  int quad = lane >> 4, l16 = lane & 15;
  int nb0 = cog * 8 + w * 2;

  int abase[MT];
#pragma unroll
  for (int mi = 0; mi < MT; ++mi) {
    int pl = mi * 16 + l16; if (pl > Mpix - 1) pl = Mpix - 1;
    int y = pl / W, x = pl - y * W;
    abase[mi] = (y * PC + x) * 40 + quad * 8;
  }
  f32x4 acc[MT][2] = {};

  for (int cic = 0; cic < NCIC; ++cic) {
    __syncthreads();
    for (int cell = t; cell < PR * PC; cell += 256) {
      int pr = cell / PC, pc = cell - pr * PC;
      int yin = r0 - 1 + pr, xin = pc - 1;
      if constexpr (INF32) {
        half8 v[4] = {};
        if (yin >= 0 && yin < H && xin >= 0 && xin < W) {
          const float4* src = (const float4*)((const float*)inv +
              (size_t)n * H * W * CI + ((size_t)yin * W + xin) * CI + cic * 32);
#pragma unroll
          for (int j = 0; j < 4; ++j) {
            float4 a = src[j * 2], c = src[j * 2 + 1];
            v[j][0] = (f16)a.x; v[j][1] = (f16)a.y; v[j][2] = (f16)a.z; v[j][3] = (f16)a.w;
            v[j][4] = (f16)c.x; v[j][5] = (f16)c.y; v[j][6] = (f16)c.z; v[j][7] = (f16)c.w;
          }
        }
        half8* dst = (half8*)(Ap + cell * 40);
        dst[0] = v[0]; dst[1] = v[1]; dst[2] = v[2]; dst[3] = v[3];
      } else {
        uint4 d0 = {0,0,0,0}, d1 = {0,0,0,0}, d2 = {0,0,0,0}, d3 = {0,0,0,0};
        if (yin >= 0 && yin < H && xin >= 0 && xin < W) {
          const uint4* src = (const uint4*)((const f16*)inv +
              (size_t)n * H * W * CI + ((size_t)yin * W + xin) * CI + cic * 32);
          d0 = src[0]; d1 = src[1]; d2 = src[2]; d3 = src[3];
        }
        uint4* dst = (uint4*)(Ap + cell * 40);
        dst[0] = d0; dst[1] = d1; dst[2] = d2; dst[3] = d3;
      }
    }
    __syncthreads();
    const f16* wfc = wf + (size_t)(cic * 9) * NBB * 512;
#pragma unroll
    for (int ky = 0; ky < 3; ++ky)
#pragma unroll
      for (int kx = 0; kx < 3; ++kx) {
        int kk = ky * 3 + kx;
        half8 bf0 = *(const half8*)(wfc + ((size_t)(kk * NBB + nb0) * 64 + lane) * 8);
        half8 bf1 = *(const half8*)(wfc + ((size_t)(kk * NBB + nb0 + 1) * 64 + lane) * 8);
        int shift = (ky * PC + kx) * 40;
#pragma unroll
        for (int mi = 0; mi < MT; ++mi) {
          half8 af = *(const half8*)(Ap + abase[mi] + shift);
          acc[mi][0] = MFMA16(af, bf0, acc[mi][0]);
          acc[mi][1] = MFMA16(af, bf1, acc[mi][1]);
        }
      }
  }
  // ---- epilogue: bias+relu into LDS, then 2x2 maxpool -> global ----
  int co_w = co0 + w * 32;
  float bv0 = bias[co_w + l16];
  float bv1 = bias[co_w + 16 + l16];
  __syncthreads();                               // all Ap reads done; reuse as pb
#pragma unroll
  for (int mi = 0; mi < MT; ++mi)
#pragma unroll
    for (int r = 0; r < 4; ++r) {
      int p = mi * 16 + quad * 4 + r;
      if (p < Mpix) {
        float v0 = acc[mi][0][r] + bv0; v0 = v0 > 0.f ? v0 : 0.f;
        float v1 = acc[mi][1][r] + bv1; v1 = v1 > 0.f ? v1 : 0.f;
        pb[p * 136 + w * 32 + l16] = (f16)v0;
        pb[p * 136 + w * 32 + 16 + l16] = (f16)v1;
      }
    }
  __syncthreads();
  for (int i = t; i < PW * 64; i += 256) {
    int px = i >> 6, c2 = (i & 63) * 2;
    int b00 = (2 * px) * 136 + c2;
    int b10 = (W + 2 * px) * 136 + c2;
    float a0 = fmaxf((float)pb[b00], (float)pb[b00 + 136]);
    float a1 = fmaxf((float)pb[b00 + 1], (float)pb[b00 + 137]);
    float c0 = fmaxf((float)pb[b10], (float)pb[b10 + 136]);
    float c1 = fmaxf((float)pb[b10 + 1], (float)pb[b10 + 137]);
    union { f16 h[2]; unsigned u; } pk;
    pk.h[0] = (f16)fmaxf(a0, c0);
    pk.h[1] = (f16)fmaxf(a1, c1);
    size_t op = (size_t)n * POPS + ms * PW + px;
    *(unsigned*)(out1 + op * CO + co0 + c2) = pk.u;
    if constexpr (WR2)
      *(unsigned*)(out2 + op * 1024 + co0 + c2) = pk.u;
  }
}

// ======================= conv transpose 2x2 s2 (1024->512), MFMA v2 =======================
__global__ __launch_bounds__(256, 2) void convt_mfma_k(
    const f16* __restrict__ f2h, const f16* __restrict__ ctwf,
    const float* __restrict__ ctb, f16* __restrict__ scnh) {
  __shared__ f16 act[25 * 1048];           // 52,400 B
  int b = blockIdx.x;
  int ng = b & 15, n = b >> 4;
  int t = threadIdx.x, lane = t & 63, w = t >> 6;
  int quad = lane >> 4, l16 = lane & 15;
  for (int i = t; i < 25 * 128; i += 256) {
    int row = i >> 7, c8 = i & 127;
    *(half8*)(act + row * 1048 + c8 * 8) =
        *(const half8*)(f2h + ((size_t)n * 25 + row) * 1024 + c8 * 8);
  }
  __syncthreads();
  int r1 = 16 + (l16 > 8 ? 8 : l16);       // clamp: garbage rows never stored
  f32x4 acc[2][2] = {};
  const f16* wp0 = ctwf + ((size_t)((ng * 8 + w * 2 + 0) * 32) * 64 + lane) * 8;
  const f16* wp1 = ctwf + ((size_t)((ng * 8 + w * 2 + 1) * 32) * 64 + lane) * 8;
#pragma unroll 4
  for (int ks = 0; ks < 32; ++ks) {
    half8 a0 = *(const half8*)(act + l16 * 1048 + ks * 32 + quad * 8);
    half8 a1 = *(const half8*)(act + r1 * 1048 + ks * 32 + quad * 8);
    half8 b0 = *(const half8*)(wp0 + (size_t)ks * 512);
    half8 b1 = *(const half8*)(wp1 + (size_t)ks * 512);
    acc[0][0] = MFMA16(a0, b0, acc[0][0]);
    acc[1][0] = MFMA16(a1, b0, acc[1][0]);
    acc[0][1] = MFMA16(a0, b1, acc[0][1]);
    acc[1][1] = MFMA16(a1, b1, acc[1][1]);
  }
#pragma unroll
  for (int nt = 0; nt < 2; ++nt) {
    int np = ng * 128 + w * 32 + nt * 16 + l16;
    int p = np >> 9, co = np & 511;
    int a = p >> 1, bc = p & 1;
    float bb = ctb[co];
#pragma unroll
    for (int mt = 0; mt < 2; ++mt)
#pragma unroll
      for (int r = 0; r < 4; ++r) {
        int px = mt * 16 + quad * 4 + r;
        if (px < 25) {
          int ph = px / 5, pw = px - ph * 5;
          int opx = (2 * ph + a) * 10 + 2 * pw + bc;
          scnh[((size_t)n * 100 + opx) * 1024 + 512 + co] = (f16)(acc[mt][nt][r] + bb);
        }
      }
  }
}

// ======================= object SA: fused 4-layer MFMA + max (M=64 tiles) =======================
__global__ __launch_bounds__(256, 2) void sa_mfma_k(
    const float* __restrict__ oc, const float* __restrict__ ocm,
    const float* __restrict__ w1, const float* __restrict__ b1,
    const f16* __restrict__ w2h, const float* __restrict__ b2,
    const f16* __restrict__ w3h, const float* __restrict__ b3,
    const f16* __restrict__ w4h, const float* __restrict__ b4,
    float* __restrict__ obj) {
  __shared__ f16 act1[64 * 72];            // 9,216 B [pt][K=64]
  __shared__ f16 act2[64 * 136];           // 17,408 B [pt][K=128]
  __shared__ f16 act3[64 * 264];           // 33,792 B [pt][K=256]
  __shared__ float pcx[64], pcy[64];
  int b = blockIdx.x;                      // 1024 = 32 n * 32 chunks of 64 pts
  int n = b >> 5, pb = (b & 31) * 64;
  int t = threadIdx.x, lane = t & 63, w = t >> 6;
  int quad = lane >> 4, l16 = lane & 15;
  if (t < 64) {
    pcx[t] = oc[((size_t)n * OPP + pb + t) * 2 + 0] - ocm[n * 2 + 0];
    pcy[t] = oc[((size_t)n * OPP + pb + t) * 2 + 1] - ocm[n * 2 + 1];
  }
  __syncthreads();
  {                                        // layer1: 2 -> 64 for 64 points
    int c = t & 63, pg = t >> 6;
    float wx = w1[c * 2], wy = w1[c * 2 + 1], bb = b1[c];
#pragma unroll
    for (int j = 0; j < 16; ++j) {
      int p = pg * 16 + j;
      act1[p * 72 + c] = (f16)fmaxf(fmaf(wx, pcx[p], fmaf(wy, pcy[p], bb)), 0.0f);
    }
  }
  __syncthreads();
  {                                        // layer2: M=64, K=64, N=128; wave n-range 32
    int n0 = w * 32;
    f32x4 acc[4][2] = {};
#pragma unroll
    for (int ks = 0; ks < 2; ++ks) {
      half8 a[4];
#pragma unroll
      for (int mt = 0; mt < 4; ++mt)
        a[mt] = *(const half8*)(act1 + (mt * 16 + l16) * 72 + ks * 32 + quad * 8);
#pragma unroll
      for (int nt = 0; nt < 2; ++nt) {
        half8 bf = *(const half8*)(w2h + (size_t)(n0 + nt * 16 + l16) * 64 + ks * 32 + quad * 8);
#pragma unroll
        for (int mt = 0; mt < 4; ++mt)
          acc[mt][nt] = MFMA16(a[mt], bf, acc[mt][nt]);
      }
    }
#pragma unroll
    for (int nt = 0; nt < 2; ++nt) {
      int col = n0 + nt * 16 + l16;
      float bb = b2[col];
#pragma unroll
      for (int mt = 0; mt < 4; ++mt)
#pragma unroll
        for (int r = 0; r < 4; ++r)
          act2[(mt * 16 + quad * 4 + r) * 136 + col] = (f16)fmaxf(acc[mt][nt][r] + bb, 0.0f);
    }
  }
  __syncthreads();
  {                                        // layer3: M=64, K=128, N=256; wave n-range 64
    int n0 = w * 64;
    f32x4 acc[4][4] = {};
#pragma unroll
    for (int ks = 0; ks < 4; ++ks) {
      half8 a[4];
#pragma unroll
      for (int mt = 0; mt < 4; ++mt)
        a[mt] = *(const half8*)(act2 + (mt * 16 + l16) * 136 + ks * 32 + quad * 8);
#pragma unroll
      for (int nt = 0; nt < 4; ++nt) {
        half8 bf = *(const half8*)(w3h + (size_t)(n0 + nt * 16 + l16) * 128 + ks * 32 + quad * 8);
#pragma unroll
        for (int mt = 0; mt < 4; ++mt)
          acc[mt][nt] = MFMA16(a[mt], bf, acc[mt][nt]);
      }
    }
#pragma unroll
    for (int nt = 0; nt < 4; ++nt) {
      int col = n0 + nt * 16 + l16;
      float bb = b3[col];
#pragma unroll
      for (int mt = 0; mt < 4; ++mt)
#pragma unroll
        for (int r = 0; r < 4; ++r)
          act3[(mt * 16 + quad * 4 + r) * 264 + col] = (f16)fmaxf(acc[mt][nt][r] + bb, 0.0f);
    }
  }
  __syncthreads();
  {                                        // layer4: M=64, K=256, N=512; wave n-range 128; + max
    int n0 = w * 128;
    f32x4 acc[4][8] = {};
#pragma unroll
    for (int ks = 0; ks < 8; ++ks) {
      half8 a[4];
#pragma unroll
      for (int mt = 0; mt < 4; ++mt)
        a[mt] = *(const half8*)(act3 + (mt * 16 + l16) * 264 + ks * 32 + quad * 8);
#pragma unroll
      for (int nt = 0; nt < 8; ++nt) {
        half8 bf = *(const half8*)(w4h + (size_t)(n0 + nt * 16 + l16) * 256 + ks * 32 + quad * 8);
#pragma unroll
        for (int mt = 0; mt < 4; ++mt)
          acc[mt][nt] = MFMA16(a[mt], bf, acc[mt][nt]);
      }
    }
#pragma unroll
    for (int nt = 0; nt < 8; ++nt) {
      int col = n0 + nt * 16 + l16;
      float bb = b4[col];
      float v = 0.0f;
#pragma unroll
      for (int mt = 0; mt < 4; ++mt)
#pragma unroll
        for (int r = 0; r < 4; ++r)
          v = fmaxf(v, acc[mt][nt][r] + bb);
      v = fmaxf(v, 0.0f);
      v = fmaxf(v, __shfl_xor(v, 16));
      v = fmaxf(v, __shfl_xor(v, 32));
      if (quad == 0)
        atomicMax((int*)obj + (size_t)n * 512 + col, __float_as_int(v));
    }
  }
}

// ======================= obj-dot precompute: odw[n][co] = obj[n]·w1raw[co,1024:1536] + b1 =======
__global__ __launch_bounds__(256) void odprep_k(
    const float* __restrict__ obj, const float* __restrict__ w1raw,
    const float* __restrict__ b1, float* __restrict__ odw, float* __restrict__ wab) {
  int co = blockIdx.x;
  int t = threadIdx.x, lane = t & 63, w = t >> 6;
  const float* wr = w1raw + (size_t)co * 1538 + 1024;
  float2 wv[4];
#pragma unroll
  for (int j = 0; j < 4; ++j) wv[j] = *(const float2*)(wr + lane * 8 + j * 2);
  float bb = b1[co];
  for (int i = 0; i < 8; ++i) {
    int n = w * 8 + i;
    const float* ob = obj + (size_t)n * 512 + lane * 8;
    float od = 0.0f;
#pragma unroll
    for (int j = 0; j < 4; ++j) {
      float2 ov = *(const float2*)(ob + j * 2);
      od = fmaf(wv[j].x, ov.x, od);
      od = fmaf(wv[j].y, ov.y, od);
    }
    od += __shfl_xor(od, 1);  od += __shfl_xor(od, 2);
    od += __shfl_xor(od, 4);  od += __shfl_xor(od, 8);
    od += __shfl_xor(od, 16); od += __shfl_xor(od, 32);
    if (lane == 0) odw[(size_t)n * 1024 + co] = od + bb;
  }
  if (t == 0) { wab[co * 2] = wr[512]; wab[co * 2 + 1] = wr[513]; }
}

// ======================= classifier layer 1 (1538 -> 1024), MFMA =======================
// grid = 1024; o8 = b&7 so all blocks sharing a w1h octant slice land on ONE XCD.
__global__ __launch_bounds__(256) void cls1_mfma_k(
    const f16* __restrict__ scnh, const float* __restrict__ odw,
    const float* __restrict__ wab, const float* __restrict__ pos,
    const f16* __restrict__ w1h, f16* __restrict__ h1h) {
  __shared__ f16 act[25 * 1032];           // 51,600 B
  __shared__ float odl[128], wAl[128], wBl[128];
  int b = blockIdx.x;
  int o8 = b & 7, mq = (b >> 3) & 3, n = b >> 5;
  int co0 = o8 * 128, p0 = mq * 25;
  int t = threadIdx.x, lane = t & 63, w = t >> 6;
  int quad = lane >> 4, l16 = lane & 15;
  for (int i = t; i < 25 * 128; i += 256) {
    int row = i >> 7, c8 = i & 127;
    *(half8*)(act + row * 1032 + c8 * 8) =
        *(const half8*)(scnh + ((size_t)n * 100 + p0 + row) * 1024 + c8 * 8);
  }
  if (t < 128) {
    odl[t] = odw[(size_t)n * 1024 + co0 + t];
    float2 ab = *(const float2*)(wab + (size_t)(co0 + t) * 2);
    wAl[t] = ab.x; wBl[t] = ab.y;
  }
  __syncthreads();
  float posx = pos[n * 2 + 0], posy = pos[n * 2 + 1];
  f32x4 acc[2][2];
#pragma unroll
  for (int mt = 0; mt < 2; ++mt)
#pragma unroll
    for (int nt = 0; nt < 2; ++nt) {
      int cl = w * 32 + nt * 16 + l16;
      float od = odl[cl], wA = wAl[cl], wB = wBl[cl];
#pragma unroll
      for (int r = 0; r < 4; ++r) {
        int pl = mt * 16 + quad * 4 + r;
        int px = p0 + (pl < 25 ? pl : 24);         // clamped lanes never stored
        float relx = posx - (-0.5f + ((px / 10) + 0.5f) * 0.1f);
        float rely = posy - (-0.5f + ((px % 10) + 0.5f) * 0.1f);
        acc[mt][nt][r] = od + relx * wA + rely * wB;
      }
    }
  int gr0 = l16;
  int gr1 = (16 + l16 > 24) ? 24 : 16 + l16;
  const f16* wb0 = w1h + (size_t)(co0 + w * 32 + l16) * 1024 + quad * 8;
  const f16* wb1 = wb0 + (size_t)16 * 1024;
#pragma unroll 4
  for (int kq = 0; kq < 32; ++kq) {
    int k0 = kq * 32;
    half8 bf0 = *(const half8*)(wb0 + k0);
    half8 bf1 = *(const half8*)(wb1 + k0);
    half8 a0 = *(const half8*)(act + gr0 * 1032 + k0 + quad * 8);
    half8 a1 = *(const half8*)(act + gr1 * 1032 + k0 + quad * 8);
    acc[0][0] = MFMA16(a0, bf0, acc[0][0]);
    acc[1][0] = MFMA16(a1, bf0, acc[1][0]);
    acc[0][1] = MFMA16(a0, bf1, acc[0][1]);
    acc[1][1] = MFMA16(a1, bf1, acc[1][1]);
  }
#pragma unroll
  for (int mt = 0; mt < 2; ++mt)
#pragma unroll
    for (int nt = 0; nt < 2; ++nt) {
      int co = co0 + w * 32 + nt * 16 + l16;
#pragma unroll
      for (int r = 0; r < 4; ++r) {
        int pl = mt * 16 + quad * 4 + r;
        if (pl < 25)
          h1h[((size_t)n * 100 + p0 + pl) * 1024 + co] = (f16)fmaxf(acc[mt][nt][r], 0.0f);
      }
    }
}

// ======================= classifier layer 2 (1024 -> 256), MFMA, barrier-free =======================
__global__ __launch_bounds__(256) void cls2_mfma_k(
    const f16* __restrict__ h1h, const f16* __restrict__ w2h16,
    const float* __restrict__ b2, f16* __restrict__ h2h) {
  __shared__ f16 act[25 * 1032];           // 51,600 B
  int b = blockIdx.x;
  int ng = b & 1, mq = (b >> 1) & 3, n = b >> 3;
  int co0 = ng * 128, p0 = mq * 25;
  int t = threadIdx.x, lane = t & 63, w = t >> 6;
  int quad = lane >> 4, l16 = lane & 15;
  for (int i = t; i < 25 * 128; i += 256) {
    int row = i >> 7, c8 = i & 127;
    *(half8*)(act + row * 1032 + c8 * 8) =
        *(const half8*)(h1h + ((size_t)n * 100 + p0 + row) * 1024 + c8 * 8);
  }
  __syncthreads();
  f32x4 acc[2][2] = {};
  int gr0 = l16;
  int gr1 = (16 + l16 > 24) ? 24 : 16 + l16;     // clamped rows never stored
  const f16* wb0 = w2h16 + (size_t)(co0 + w * 32 + l16) * 1024 + quad * 8;
  const f16* wb1 = wb0 + (size_t)16 * 1024;
#pragma unroll 4
  for (int kq = 0; kq < 32; ++kq) {
    int k0 = kq * 32;
    half8 bf0 = *(const half8*)(wb0 + k0);
    half8 bf1 = *(const half8*)(wb1 + k0);
    half8 a0 = *(const half8*)(act + gr0 * 1032 + k0 + quad * 8);
    half8 a1 = *(const half8*)(act + gr1 * 1032 + k0 + quad * 8);
    acc[0][0] = MFMA16(a0, bf0, acc[0][0]);
    acc[1][0] = MFMA16(a1, bf0, acc[1][0]);
    acc[0][1] = MFMA16(a0, bf1, acc[0][1]);
    acc[1][1] = MFMA16(a1, bf1, acc[1][1]);
  }
#pragma unroll
  for (int mt = 0; mt < 2; ++mt)
#pragma unroll
    for (int nt = 0; nt < 2; ++nt) {
      int co = co0 + w * 32 + nt * 16 + l16;
      float bb = b2[co];
#pragma unroll
      for (int r = 0; r < 4; ++r) {
        int pl = mt * 16 + quad * 4 + r;
        if (pl < 25)
          h2h[((size_t)n * 100 + p0 + pl) * 256 + co] = (f16)fmaxf(acc[mt][nt][r] + bb, 0.0f);
      }
    }
}

// ======================= classifier layer 3 (256 -> 1) =======================
__global__ void cls3_k(const f16* __restrict__ h2h, const float* __restrict__ w3,
                       const float* __restrict__ b3, float* __restrict__ out) {
  int n = blockIdx.x, t = threadIdx.x;
  if (t < 100) {
    float acc = b3[0];
    const f16* hp = &h2h[((size_t)n * 100 + t) * 256];
    for (int k = 0; k < 256; ++k) acc = fmaf((float)hp[k], w3[k], acc);
    out[n * 100 + t] = acc;
  }
}

// ======================= launch =======================
extern "C" void kernel_launch(void* const* d_in, const int* in_sizes, int n_in,
                              void* d_out, int out_size, void* d_ws, size_t ws_size,
                              hipStream_t stream) {
  const float* sc      = (const float*)d_in[0];
  const float* oc      = (const float*)d_in[1];
  const float* pos     = (const float*)d_in[2];
  const float* mlp_w1  = (const float*)d_in[3];
  const float* mlp_b1  = (const float*)d_in[4];
  const float* mlp_w2  = (const float*)d_in[5];
  const float* mlp_b2  = (const float*)d_in[6];
  const float* conv1_w = (const float*)d_in[7];
  const float* conv1_b = (const float*)d_in[8];
  const float* conv2_w = (const float*)d_in[9];
  const float* conv2_b = (const float*)d_in[10];
  const float* convt_w = (const float*)d_in[11];
  const float* convt_b = (const float*)d_in[12];
  const float* sa_w1   = (const float*)d_in[13];
  const float* sa_b1   = (const float*)d_in[14];
  const float* sa_w2   = (const float*)d_in[15];
  const float* sa_b2   = (const float*)d_in[16];
  const float* sa_w3   = (const float*)d_in[17];
  const float* sa_b3   = (const float*)d_in[18];
  const float* sa_w4   = (const float*)d_in[19];
  const float* sa_b4   = (const float*)d_in[20];
  const float* cls_w1  = (const float*)d_in[21];
  const float* cls_b1  = (const float*)d_in[22];
  const float* cls_w2  = (const float*)d_in[23];
  const float* cls_b2  = (const float*)d_in[24];
  const float* cls_w3  = (const float*)d_in[25];
  const float* cls_b3  = (const float*)d_in[26];

  float* ws = (float*)d_ws;
  // ---- workspace layout (float units) ----
  f16*   w1h   = (f16*)ws;                         // 589,824 f (conv1 B-frag)
  f16*   w2h   = (f16*)(ws + 589824);              // 2,359,296 f (conv2 B-frag; reused: h1h)
  f16*   mw2h  = (f16*)(ws + 2949120);             // 16,384 f
  f16*   saw2h = (f16*)(ws + 2965504);             // 4,096 f
  f16*   saw3h = (f16*)(ws + 2969600);             // 16,384 f
  f16*   saw4h = (f16*)(ws + 2985984);             // 65,536 f
  f16*   cw1h  = (f16*)(ws + 3051520);             // 524,288 f
  f16*   ctwh  = (f16*)(ws + 3575808);             // 1,048,576 f (B-frag layout)
  f16*   cw2h  = (f16*)(ws + 4624384);             // 131,072 f ([256][1024] fp16)
  float* obj   = ws + 4870144;                     // 16,384 f (adjacent to voxg -> one memset)
  float* big   = ws + 4886528;                     // 3,276,800 f (voxg; later odw/wab)
  f16*   voxh  = (f16*)(ws + 8163328);             // 819,200 f (reused: f2h)
  f16*   f1h   = (f16*)(ws + 8982528);             // 819,200 f
  f16*   scnh  = (f16*)(ws + 9801728);             // 1,638,400 f (reused: h2h)
  float* ocm   = ws + 11456512;                    // 64 f

  float* voxg  = big;                              // fp32 voxel buffer [32][400][256]
  f16*   f2h   = voxh;                             // conv2 fused-pool out
  f16*   h1h   = w2h;                              // cls1 out (w2h dead after conv2)
  f16*   h2h   = scnh;                             // cls2 out (scnh dead after cls1)
  float* odw   = big + 2097152;                    // 32,768 f (voxg dead after conv1)
  float* wab   = big + 2129920;                    // 2,048 f
  float* outp  = (float*)d_out;

  // single fused prep (all weight conversions + ocmean) + single memset (obj+voxg contiguous)
  hipMemsetAsync(obj, 0, (size_t)(16384 + 3276800) * 4, stream);
  prepfuse_k<<<3616, 256, 0, stream>>>(mlp_w2, sa_w2, sa_w3, sa_w4, cls_w2, cls_w1,
                                       convt_w, conv1_w, conv2_w, oc,
                                       mw2h, saw2h, saw3h, saw4h, cw2h, cw1h,
                                       ctwh, w1h, w2h, ocm);

  pointnet_lds_k<<<1024, 256, 0, stream>>>(sc, mlp_w1, mlp_b1, mw2h, mlp_b2, voxg);

  // conv1 (fp32 input, fused pool, writes f1h + scnh): grid 32*10*4 = 1280
  convpool_k<20, 20, 256, 512, 10, true, true><<<1280, 256, 10880, stream>>>(
      voxg, w1h, conv1_b, f1h, scnh);
  // conv2 (f16 input, fused pool, writes f2h): grid 32*5*8 = 1280
  convpool_k<10, 10, 512, 1024, 5, false, false><<<1280, 256, 5440, stream>>>(
      f1h, w2h, conv2_b, f2h, nullptr);

  convt_mfma_k<<<512, 256, 0, stream>>>(f2h, ctwh, convt_b, scnh);

  sa_mfma_k<<<1024, 256, 0, stream>>>(oc, ocm, sa_w1, sa_b1, saw2h, sa_b2,
                                      saw3h, sa_b3, saw4h, sa_b4, obj);
  odprep_k<<<1024, 256, 0, stream>>>(obj, cls_w1, cls_b1, odw, wab);

  cls1_mfma_k<<<1024, 256, 0, stream>>>(scnh, odw, wab, pos, cw1h, h1h);
  cls2_mfma_k<<<256, 256, 0, stream>>>(h1h, cw2h, cls_b2, h2h);
  cls3_k<<<32, 128, 0, stream>>>(h2h, cls_w3, cls_b3, outp);
}